// Round 1
// baseline (1015.471 us; speedup 1.0000x reference)
//
#include <hip/hip_runtime.h>
#include <hip/hip_bf16.h>
#include <math.h>

// ---------------- degree / norm ----------------
__global__ void k_count(const int* __restrict__ dst, int E, int* __restrict__ cnt) {
    int i = blockIdx.x * blockDim.x + threadIdx.x;
    if (i < E) atomicAdd(&cnt[dst[i]], 1);
}

__global__ void k_dinv(const int* __restrict__ cnt, float* __restrict__ dinv, int N) {
    int i = blockIdx.x * blockDim.x + threadIdx.x;
    if (i < N) dinv[i] = rsqrtf((float)(cnt[i] + 1));  // +1 = self loop
}

// ---------------- scan (row offsets) ----------------
#define SCAN_B 256
__global__ void k_scan1(const int* __restrict__ cnt, int* __restrict__ partial, int N) {
    __shared__ int lds[SCAN_B];
    int i = blockIdx.x * SCAN_B + threadIdx.x;
    lds[threadIdx.x] = (i < N) ? cnt[i] : 0;
    __syncthreads();
    for (int s = SCAN_B / 2; s > 0; s >>= 1) {
        if (threadIdx.x < s) lds[threadIdx.x] += lds[threadIdx.x + s];
        __syncthreads();
    }
    if (threadIdx.x == 0) partial[blockIdx.x] = lds[0];
}

__global__ void k_scan2(int* __restrict__ partial, int nb) {
    __shared__ int lds[1024];
    int t = threadIdx.x;
    if (t < nb) lds[t] = partial[t];
    __syncthreads();
    if (t == 0) {
        int run = 0;
        for (int i = 0; i < nb; i++) { int v = lds[i]; lds[i] = run; run += v; }
    }
    __syncthreads();
    if (t < nb) partial[t] = lds[t];
}

__global__ void k_scan3(const int* __restrict__ cnt, const int* __restrict__ partial,
                        int* __restrict__ row_off, int N, int E) {
    __shared__ int lds[SCAN_B];
    int i = blockIdx.x * SCAN_B + threadIdx.x;
    int v = (i < N) ? cnt[i] : 0;
    int val = v;
    lds[threadIdx.x] = val;
    __syncthreads();
    for (int s = 1; s < SCAN_B; s <<= 1) {
        int add = (threadIdx.x >= s) ? lds[threadIdx.x - s] : 0;
        __syncthreads();
        val += add;
        lds[threadIdx.x] = val;
        __syncthreads();
    }
    if (i < N) row_off[i] = partial[blockIdx.x] + val - v;  // exclusive
    if (blockIdx.x == 0 && threadIdx.x == 0) row_off[N] = E;
}

__global__ void k_fill(const int* __restrict__ src, const int* __restrict__ dst, int E,
                       const int* __restrict__ row_off, int* __restrict__ cursor,
                       int* __restrict__ csr_src) {
    int i = blockIdx.x * blockDim.x + threadIdx.x;
    if (i < E) {
        int d = dst[i];
        int pos = row_off[d] + atomicAdd(&cursor[d], 1);
        csr_src[pos] = src[i];
    }
}

// ---------------- GEMM: Y[N,128] = X[N,128] @ W[128,128] ----------------
__global__ __launch_bounds__(256) void k_gemm128(const float* __restrict__ X,
                                                 const float* __restrict__ W,
                                                 float* __restrict__ Y, int N) {
    __shared__ float Wl[128 * 128];
    int t = threadIdx.x;
#pragma unroll
    for (int i = 0; i < 16; i++) {
        int idx = (i * 256 + t) * 4;
        *(float4*)&Wl[idx] = *(const float4*)&W[idx];
    }
    __syncthreads();

    int row0 = blockIdx.x * 64 + (t >> 4) * 4;
    int col0 = (t & 15) * 8;

    float acc[4][8];
#pragma unroll
    for (int i = 0; i < 4; i++)
#pragma unroll
        for (int j = 0; j < 8; j++) acc[i][j] = 0.f;

    for (int k = 0; k < 128; k += 4) {
        float4 a[4];
#pragma unroll
        for (int i = 0; i < 4; i++) {
            int r = row0 + i; if (r >= N) r = N - 1;
            a[i] = *(const float4*)&X[(size_t)r * 128 + k];
        }
#pragma unroll
        for (int kk = 0; kk < 4; kk++) {
            float4 b0 = *(const float4*)&Wl[(k + kk) * 128 + col0];
            float4 b1 = *(const float4*)&Wl[(k + kk) * 128 + col0 + 4];
#pragma unroll
            for (int i = 0; i < 4; i++) {
                float av = (kk == 0) ? a[i].x : (kk == 1) ? a[i].y : (kk == 2) ? a[i].z : a[i].w;
                acc[i][0] += av * b0.x; acc[i][1] += av * b0.y;
                acc[i][2] += av * b0.z; acc[i][3] += av * b0.w;
                acc[i][4] += av * b1.x; acc[i][5] += av * b1.y;
                acc[i][6] += av * b1.z; acc[i][7] += av * b1.w;
            }
        }
    }
#pragma unroll
    for (int i = 0; i < 4; i++) {
        int r = row0 + i;
        if (r < N) {
            float4 o0 = {acc[i][0], acc[i][1], acc[i][2], acc[i][3]};
            float4 o1 = {acc[i][4], acc[i][5], acc[i][6], acc[i][7]};
            *(float4*)&Y[(size_t)r * 128 + col0] = o0;
            *(float4*)&Y[(size_t)r * 128 + col0 + 4] = o1;
        }
    }
}

// ---------------- aggregation: one wave per node ----------------
__global__ __launch_bounds__(256) void k_agg(const float* __restrict__ XW,
                                             const float* __restrict__ dinv,
                                             const int* __restrict__ row_off,
                                             const int* __restrict__ csr_src,
                                             const float* __restrict__ bias,
                                             float* __restrict__ OUT, int N, int do_relu) {
    int wave = (blockIdx.x * blockDim.x + threadIdx.x) >> 6;
    int lane = threadIdx.x & 63;
    if (wave >= N) return;
    int n = wave;
    int beg = row_off[n], end = row_off[n + 1];
    float din = dinv[n];
    float ax = 0.f, ay = 0.f;
    for (int e = beg; e < end; ++e) {
        int s = csr_src[e];
        float ds = dinv[s];
        float2 v = *(const float2*)&XW[(size_t)s * 128 + lane * 2];
        ax += ds * v.x; ay += ds * v.y;
    }
    float2 vs = *(const float2*)&XW[(size_t)n * 128 + lane * 2];
    ax += din * vs.x; ay += din * vs.y;
    float b0 = bias[lane * 2], b1 = bias[lane * 2 + 1];
    float ox = din * ax + b0, oy = din * ay + b1;
    if (do_relu) { ox = fmaxf(ox, 0.f); oy = fmaxf(oy, 0.f); }
    float2 o = {ox, oy};
    *(float2*)&OUT[(size_t)n * 128 + lane * 2] = o;
}

// ---------------- mean pool per graph ----------------
__global__ void k_pool(const float* __restrict__ H, const int* __restrict__ batch, int N,
                       float* __restrict__ pooled) {
    int g = blockIdx.x;   // 64 graphs
    int t = threadIdx.x;  // 128 features
    __shared__ int sh[2];
    if (t == 0) {
        int lo = 0, hi = N;
        while (lo < hi) { int m = (lo + hi) >> 1; if (batch[m] < g) lo = m + 1; else hi = m; }
        sh[0] = lo;
        lo = 0; hi = N;
        while (lo < hi) { int m = (lo + hi) >> 1; if (batch[m] < g + 1) lo = m + 1; else hi = m; }
        sh[1] = lo;
    }
    __syncthreads();
    int beg = sh[0], end = sh[1];
    float s = 0.f;
    for (int nn = beg; nn < end; ++nn) s += H[(size_t)nn * 128 + t];
    float cnt = (float)((end - beg) > 0 ? (end - beg) : 1);
    pooled[g * 128 + t] = s / cnt;
}

// ---------------- final MLP ----------------
__global__ void k_mlp(const float* __restrict__ pooled, const float* __restrict__ Wl1,
                      const float* __restrict__ bl1, const float* __restrict__ Wl2,
                      const float* __restrict__ bl2, float* __restrict__ out) {
    int g = blockIdx.x;   // 64
    int j = threadIdx.x;  // 64
    float acc = 0.f;
#pragma unroll 8
    for (int k = 0; k < 128; k++) acc += pooled[g * 128 + k] * Wl1[k * 64 + j];
    float h = fmaxf(acc + bl1[j], 0.f);
    float v = h * Wl2[j];
#pragma unroll
    for (int off = 32; off > 0; off >>= 1) v += __shfl_down(v, off);
    if (j == 0) out[g] = 1.f / (1.f + expf(-(v + bl2[0])));
}

// ---------------- launch ----------------
extern "C" void kernel_launch(void* const* d_in, const int* in_sizes, int n_in,
                              void* d_out, int out_size, void* d_ws, size_t ws_size,
                              hipStream_t stream) {
    const float* x    = (const float*)d_in[0];
    const int*   edge = (const int*)d_in[1];
    const int*   batch= (const int*)d_in[2];
    const float* W1   = (const float*)d_in[3];
    const float* b1   = (const float*)d_in[4];
    const float* W2   = (const float*)d_in[5];
    const float* b2   = (const float*)d_in[6];
    const float* Wl1  = (const float*)d_in[7];
    const float* bl1  = (const float*)d_in[8];
    const float* Wl2  = (const float*)d_in[9];
    const float* bl2  = (const float*)d_in[10];
    float* out = (float*)d_out;

    int N = in_sizes[0] / 128;
    int E = in_sizes[1] / 2;
    const int* src = edge;
    const int* dst = edge + E;

    char* ws = (char*)d_ws;
    size_t off = 0;
    auto alloc = [&](size_t bytes) { void* p = ws + off; off += (bytes + 511) & ~(size_t)511; return p; };
    float* dinv    = (float*)alloc((size_t)N * 4);
    float* bufA    = (float*)alloc((size_t)N * 128 * 4);
    float* bufB    = (float*)alloc((size_t)N * 128 * 4);
    int*   cnt     = (int*)alloc((size_t)N * 4);
    int*   cursor  = (int*)alloc((size_t)N * 4);
    int*   row_off = (int*)alloc((size_t)(N + 1) * 4);
    int*   csr_src = (int*)alloc((size_t)E * 4);
    int    nb      = (N + SCAN_B - 1) / SCAN_B;
    int*   partial = (int*)alloc((size_t)nb * 4);
    float* pooled  = (float*)alloc(64 * 128 * 4);

    hipMemsetAsync(cnt, 0, (size_t)N * 4, stream);
    hipMemsetAsync(cursor, 0, (size_t)N * 4, stream);

    k_count<<<(E + 255) / 256, 256, 0, stream>>>(dst, E, cnt);
    k_dinv<<<(N + 255) / 256, 256, 0, stream>>>(cnt, dinv, N);
    k_scan1<<<nb, SCAN_B, 0, stream>>>(cnt, partial, N);
    k_scan2<<<1, 1024, 0, stream>>>(partial, nb);
    k_scan3<<<nb, SCAN_B, 0, stream>>>(cnt, partial, row_off, N, E);
    k_fill<<<(E + 255) / 256, 256, 0, stream>>>(src, dst, E, row_off, cursor, csr_src);

    k_gemm128<<<(N + 63) / 64, 256, 0, stream>>>(x, W1, bufA, N);
    k_agg<<<(N + 3) / 4, 256, 0, stream>>>(bufA, dinv, row_off, csr_src, b1, bufB, N, 1);
    k_gemm128<<<(N + 63) / 64, 256, 0, stream>>>(bufB, W2, bufA, N);
    k_agg<<<(N + 3) / 4, 256, 0, stream>>>(bufA, dinv, row_off, csr_src, b2, bufB, N, 0);
    k_pool<<<64, 128, 0, stream>>>(bufB, batch, N, pooled);
    k_mlp<<<64, 64, 0, stream>>>(pooled, Wl1, bl1, Wl2, bl2, out);
}

// Round 2
// 669.036 us; speedup vs baseline: 1.5178x; 1.5178x over previous
//
#include <hip/hip_runtime.h>
#include <hip/hip_bf16.h>
#include <math.h>

// ---------------- degree / norm ----------------
__global__ void k_count(const int* __restrict__ dst, int E, int* __restrict__ cnt) {
    int i = blockIdx.x * blockDim.x + threadIdx.x;
    if (i < E) atomicAdd(&cnt[dst[i]], 1);
}

__global__ void k_dinv(const int* __restrict__ cnt, float* __restrict__ dinv, int N) {
    int i = blockIdx.x * blockDim.x + threadIdx.x;
    if (i < N) dinv[i] = rsqrtf((float)(cnt[i] + 1));  // +1 = self loop
}

// ---------------- scan (row offsets) ----------------
#define SCAN_B 256
__global__ void k_scan1(const int* __restrict__ cnt, int* __restrict__ partial, int N) {
    __shared__ int lds[SCAN_B];
    int i = blockIdx.x * SCAN_B + threadIdx.x;
    lds[threadIdx.x] = (i < N) ? cnt[i] : 0;
    __syncthreads();
    for (int s = SCAN_B / 2; s > 0; s >>= 1) {
        if (threadIdx.x < s) lds[threadIdx.x] += lds[threadIdx.x + s];
        __syncthreads();
    }
    if (threadIdx.x == 0) partial[blockIdx.x] = lds[0];
}

__global__ void k_scan2(int* __restrict__ partial, int nb) {
    __shared__ int lds[1024];
    int t = threadIdx.x;
    if (t < nb) lds[t] = partial[t];
    __syncthreads();
    if (t == 0) {
        int run = 0;
        for (int i = 0; i < nb; i++) { int v = lds[i]; lds[i] = run; run += v; }
    }
    __syncthreads();
    if (t < nb) partial[t] = lds[t];
}

__global__ void k_scan3(const int* __restrict__ cnt, const int* __restrict__ partial,
                        int* __restrict__ row_off, int N, int E) {
    __shared__ int lds[SCAN_B];
    int i = blockIdx.x * SCAN_B + threadIdx.x;
    int v = (i < N) ? cnt[i] : 0;
    int val = v;
    lds[threadIdx.x] = val;
    __syncthreads();
    for (int s = 1; s < SCAN_B; s <<= 1) {
        int add = (threadIdx.x >= s) ? lds[threadIdx.x - s] : 0;
        __syncthreads();
        val += add;
        lds[threadIdx.x] = val;
        __syncthreads();
    }
    if (i < N) row_off[i] = partial[blockIdx.x] + val - v;  // exclusive
    if (blockIdx.x == 0 && threadIdx.x == 0) row_off[N] = E;
}

__global__ void k_fill(const int* __restrict__ src, const int* __restrict__ dst, int E,
                       const int* __restrict__ row_off, int* __restrict__ cursor,
                       int* __restrict__ csr_src) {
    int i = blockIdx.x * blockDim.x + threadIdx.x;
    if (i < E) {
        int d = dst[i];
        int pos = row_off[d] + atomicAdd(&cursor[d], 1);
        csr_src[pos] = src[i];
    }
}

// ---------------- GEMM: Y[N,128] = X[N,128] @ W[128,128] ----------------
__global__ __launch_bounds__(256) void k_gemm128(const float* __restrict__ X,
                                                 const float* __restrict__ W,
                                                 float* __restrict__ Y, int N) {
    __shared__ float Wl[128 * 128];
    int t = threadIdx.x;
#pragma unroll
    for (int i = 0; i < 16; i++) {
        int idx = (i * 256 + t) * 4;
        *(float4*)&Wl[idx] = *(const float4*)&W[idx];
    }
    __syncthreads();

    int row0 = blockIdx.x * 64 + (t >> 4) * 4;
    int col0 = (t & 15) * 8;

    float acc[4][8];
#pragma unroll
    for (int i = 0; i < 4; i++)
#pragma unroll
        for (int j = 0; j < 8; j++) acc[i][j] = 0.f;

    for (int k = 0; k < 128; k += 4) {
        float4 a[4];
#pragma unroll
        for (int i = 0; i < 4; i++) {
            int r = row0 + i; if (r >= N) r = N - 1;
            a[i] = *(const float4*)&X[(size_t)r * 128 + k];
        }
#pragma unroll
        for (int kk = 0; kk < 4; kk++) {
            float4 b0 = *(const float4*)&Wl[(k + kk) * 128 + col0];
            float4 b1 = *(const float4*)&Wl[(k + kk) * 128 + col0 + 4];
#pragma unroll
            for (int i = 0; i < 4; i++) {
                float av = (kk == 0) ? a[i].x : (kk == 1) ? a[i].y : (kk == 2) ? a[i].z : a[i].w;
                acc[i][0] += av * b0.x; acc[i][1] += av * b0.y;
                acc[i][2] += av * b0.z; acc[i][3] += av * b0.w;
                acc[i][4] += av * b1.x; acc[i][5] += av * b1.y;
                acc[i][6] += av * b1.z; acc[i][7] += av * b1.w;
            }
        }
    }
#pragma unroll
    for (int i = 0; i < 4; i++) {
        int r = row0 + i;
        if (r < N) {
            float4 o0 = {acc[i][0], acc[i][1], acc[i][2], acc[i][3]};
            float4 o1 = {acc[i][4], acc[i][5], acc[i][6], acc[i][7]};
            *(float4*)&Y[(size_t)r * 128 + col0] = o0;
            *(float4*)&Y[(size_t)r * 128 + col0 + 4] = o1;
        }
    }
}

// ---------------- aggregation: one wave per node ----------------
__global__ __launch_bounds__(256) void k_agg(const float* __restrict__ XW,
                                             const float* __restrict__ dinv,
                                             const int* __restrict__ row_off,
                                             const int* __restrict__ csr_src,
                                             const float* __restrict__ bias,
                                             float* __restrict__ OUT, int N, int do_relu) {
    int wave = (blockIdx.x * blockDim.x + threadIdx.x) >> 6;
    int lane = threadIdx.x & 63;
    if (wave >= N) return;
    int n = wave;
    int beg = row_off[n], end = row_off[n + 1];
    float din = dinv[n];
    float ax = 0.f, ay = 0.f;
    for (int e = beg; e < end; ++e) {
        int s = csr_src[e];
        float ds = dinv[s];
        float2 v = *(const float2*)&XW[(size_t)s * 128 + lane * 2];
        ax += ds * v.x; ay += ds * v.y;
    }
    float2 vs = *(const float2*)&XW[(size_t)n * 128 + lane * 2];
    ax += din * vs.x; ay += din * vs.y;
    float b0 = bias[lane * 2], b1 = bias[lane * 2 + 1];
    float ox = din * ax + b0, oy = din * ay + b1;
    if (do_relu) { ox = fmaxf(ox, 0.f); oy = fmaxf(oy, 0.f); }
    float2 o = {ox, oy};
    *(float2*)&OUT[(size_t)n * 128 + lane * 2] = o;
}

// ---------------- mean pool per graph (parallel, batch sorted) ----------------
// stage 1: 1024 blocks, each scans a contiguous node chunk, register-accumulates
// per feature, flushes to pooled[g] via atomicAdd only at graph boundaries.
__global__ __launch_bounds__(128) void k_pool_partial(const float* __restrict__ H,
                                                      const int* __restrict__ batch, int N,
                                                      float* __restrict__ pooled) {
    int t = threadIdx.x;          // feature 0..127
    int chunk = (N + gridDim.x - 1) / gridDim.x;
    int beg = blockIdx.x * chunk;
    int end = beg + chunk; if (end > N) end = N;
    if (beg >= end) return;
    float acc = 0.f;
    int g = batch[beg];
    for (int nn = beg; nn < end; ++nn) {
        int gn = batch[nn];
        if (gn != g) {
            atomicAdd(&pooled[g * 128 + t], acc);
            acc = 0.f;
            g = gn;
        }
        acc += H[(size_t)nn * 128 + t];
    }
    atomicAdd(&pooled[g * 128 + t], acc);
}

// stage 2: divide by per-graph counts (binary search over sorted batch)
__global__ void k_pool_final(const int* __restrict__ batch, int N,
                             float* __restrict__ pooled) {
    int g = blockIdx.x;   // 64 graphs
    int t = threadIdx.x;  // 128 features
    __shared__ int sh[2];
    if (t == 0) {
        int lo = 0, hi = N;
        while (lo < hi) { int m = (lo + hi) >> 1; if (batch[m] < g) lo = m + 1; else hi = m; }
        sh[0] = lo;
        lo = 0; hi = N;
        while (lo < hi) { int m = (lo + hi) >> 1; if (batch[m] < g + 1) lo = m + 1; else hi = m; }
        sh[1] = lo;
    }
    __syncthreads();
    float cnt = (float)(sh[1] - sh[0]);
    if (cnt < 1.f) cnt = 1.f;
    pooled[g * 128 + t] /= cnt;
}

// ---------------- final MLP ----------------
__global__ void k_mlp(const float* __restrict__ pooled, const float* __restrict__ Wl1,
                      const float* __restrict__ bl1, const float* __restrict__ Wl2,
                      const float* __restrict__ bl2, float* __restrict__ out) {
    int g = blockIdx.x;   // 64
    int j = threadIdx.x;  // 64
    float acc = 0.f;
#pragma unroll 8
    for (int k = 0; k < 128; k++) acc += pooled[g * 128 + k] * Wl1[k * 64 + j];
    float h = fmaxf(acc + bl1[j], 0.f);
    float v = h * Wl2[j];
#pragma unroll
    for (int off = 32; off > 0; off >>= 1) v += __shfl_down(v, off);
    if (j == 0) out[g] = 1.f / (1.f + expf(-(v + bl2[0])));
}

// ---------------- launch ----------------
extern "C" void kernel_launch(void* const* d_in, const int* in_sizes, int n_in,
                              void* d_out, int out_size, void* d_ws, size_t ws_size,
                              hipStream_t stream) {
    const float* x    = (const float*)d_in[0];
    const int*   edge = (const int*)d_in[1];
    const int*   batch= (const int*)d_in[2];
    const float* W1   = (const float*)d_in[3];
    const float* b1   = (const float*)d_in[4];
    const float* W2   = (const float*)d_in[5];
    const float* b2   = (const float*)d_in[6];
    const float* Wl1  = (const float*)d_in[7];
    const float* bl1  = (const float*)d_in[8];
    const float* Wl2  = (const float*)d_in[9];
    const float* bl2  = (const float*)d_in[10];
    float* out = (float*)d_out;

    int N = in_sizes[0] / 128;
    int E = in_sizes[1] / 2;
    const int* src = edge;
    const int* dst = edge + E;

    char* ws = (char*)d_ws;
    size_t off = 0;
    auto alloc = [&](size_t bytes) { void* p = ws + off; off += (bytes + 511) & ~(size_t)511; return p; };
    float* dinv    = (float*)alloc((size_t)N * 4);
    float* bufA    = (float*)alloc((size_t)N * 128 * 4);
    float* bufB    = (float*)alloc((size_t)N * 128 * 4);
    int*   cnt     = (int*)alloc((size_t)N * 4);
    int*   cursor  = (int*)alloc((size_t)N * 4);
    int*   row_off = (int*)alloc((size_t)(N + 1) * 4);
    int*   csr_src = (int*)alloc((size_t)E * 4);
    int    nb      = (N + SCAN_B - 1) / SCAN_B;
    int*   partial = (int*)alloc((size_t)nb * 4);
    float* pooled  = (float*)alloc(64 * 128 * 4);

    hipMemsetAsync(cnt, 0, (size_t)N * 4, stream);
    hipMemsetAsync(cursor, 0, (size_t)N * 4, stream);
    hipMemsetAsync(pooled, 0, 64 * 128 * 4, stream);

    k_count<<<(E + 255) / 256, 256, 0, stream>>>(dst, E, cnt);
    k_dinv<<<(N + 255) / 256, 256, 0, stream>>>(cnt, dinv, N);
    k_scan1<<<nb, SCAN_B, 0, stream>>>(cnt, partial, N);
    k_scan2<<<1, 1024, 0, stream>>>(partial, nb);
    k_scan3<<<nb, SCAN_B, 0, stream>>>(cnt, partial, row_off, N, E);
    k_fill<<<(E + 255) / 256, 256, 0, stream>>>(src, dst, E, row_off, cursor, csr_src);

    k_gemm128<<<(N + 63) / 64, 256, 0, stream>>>(x, W1, bufA, N);
    k_agg<<<(N + 3) / 4, 256, 0, stream>>>(bufA, dinv, row_off, csr_src, b1, bufB, N, 1);
    k_gemm128<<<(N + 63) / 64, 256, 0, stream>>>(bufB, W2, bufA, N);
    k_agg<<<(N + 3) / 4, 256, 0, stream>>>(bufA, dinv, row_off, csr_src, b2, bufB, N, 0);
    k_pool_partial<<<1024, 128, 0, stream>>>(bufB, batch, N, pooled);
    k_pool_final<<<64, 128, 0, stream>>>(batch, N, pooled);
    k_mlp<<<64, 64, 0, stream>>>(pooled, Wl1, bl1, Wl2, bl2, out);
}

// Round 3
// 551.672 us; speedup vs baseline: 1.8407x; 1.2127x over previous
//
#include <hip/hip_runtime.h>
#include <hip/hip_bf16.h>
#include <math.h>

typedef unsigned short u16;

__device__ __forceinline__ float b2f(u16 u) {
    union { unsigned int i; float f; } v; v.i = ((unsigned int)u) << 16; return v.f;
}
__device__ __forceinline__ u16 f2b(float f) {
    unsigned int i = __float_as_uint(f);
    unsigned int r = (i + 0x7FFFu + ((i >> 16) & 1u)) >> 16;
    return (u16)r;
}

// ---------------- degree / norm ----------------
__global__ void k_count(const int* __restrict__ dst, int E, int* __restrict__ cnt) {
    int i = blockIdx.x * blockDim.x + threadIdx.x;
    if (i < E) atomicAdd(&cnt[dst[i]], 1);
}

__global__ void k_dinv(const int* __restrict__ cnt, float* __restrict__ dinv, int N) {
    int i = blockIdx.x * blockDim.x + threadIdx.x;
    if (i < N) dinv[i] = rsqrtf((float)(cnt[i] + 1));  // +1 = self loop
}

// ---------------- scan (row offsets) ----------------
#define SCAN_B 256
__global__ void k_scan1(const int* __restrict__ cnt, int* __restrict__ partial, int N) {
    __shared__ int lds[SCAN_B];
    int i = blockIdx.x * SCAN_B + threadIdx.x;
    lds[threadIdx.x] = (i < N) ? cnt[i] : 0;
    __syncthreads();
    for (int s = SCAN_B / 2; s > 0; s >>= 1) {
        if (threadIdx.x < s) lds[threadIdx.x] += lds[threadIdx.x + s];
        __syncthreads();
    }
    if (threadIdx.x == 0) partial[blockIdx.x] = lds[0];
}

__global__ void k_scan2(int* __restrict__ partial, int nb) {
    __shared__ int lds[1024];
    int t = threadIdx.x;
    if (t < nb) lds[t] = partial[t];
    __syncthreads();
    if (t == 0) {
        int run = 0;
        for (int i = 0; i < nb; i++) { int v = lds[i]; lds[i] = run; run += v; }
    }
    __syncthreads();
    if (t < nb) partial[t] = lds[t];
}

__global__ void k_scan3(const int* __restrict__ cnt, const int* __restrict__ partial,
                        int* __restrict__ row_off, int N, int E) {
    __shared__ int lds[SCAN_B];
    int i = blockIdx.x * SCAN_B + threadIdx.x;
    int v = (i < N) ? cnt[i] : 0;
    int val = v;
    lds[threadIdx.x] = val;
    __syncthreads();
    for (int s = 1; s < SCAN_B; s <<= 1) {
        int add = (threadIdx.x >= s) ? lds[threadIdx.x - s] : 0;
        __syncthreads();
        val += add;
        lds[threadIdx.x] = val;
        __syncthreads();
    }
    if (i < N) row_off[i] = partial[blockIdx.x] + val - v;  // exclusive
    if (blockIdx.x == 0 && threadIdx.x == 0) row_off[N] = E;
}

__global__ void k_fill(const int* __restrict__ src, const int* __restrict__ dst, int E,
                       const int* __restrict__ row_off, int* __restrict__ cursor,
                       int* __restrict__ csr_src) {
    int i = blockIdx.x * blockDim.x + threadIdx.x;
    if (i < E) {
        int d = dst[i];
        int pos = row_off[d] + atomicAdd(&cursor[d], 1);
        csr_src[pos] = src[i];
    }
}

// ---------------- GEMM: Y[N,128](bf16) = X[N,128] @ W[128,128] ----------------
__device__ __forceinline__ float4 load4f(const float* p) { return *(const float4*)p; }
__device__ __forceinline__ float4 load4f(const u16* p) {
    ushort4 u = *(const ushort4*)p;
    float4 r; r.x = b2f(u.x); r.y = b2f(u.y); r.z = b2f(u.z); r.w = b2f(u.w);
    return r;
}

template <typename TIN>
__global__ __launch_bounds__(256) void k_gemm128(const TIN* __restrict__ X,
                                                 const float* __restrict__ W,
                                                 u16* __restrict__ Y, int N) {
    __shared__ float Wl[128 * 128];
    int t = threadIdx.x;
#pragma unroll
    for (int i = 0; i < 16; i++) {
        int idx = (i * 256 + t) * 4;
        *(float4*)&Wl[idx] = *(const float4*)&W[idx];
    }
    __syncthreads();

    int row0 = blockIdx.x * 64 + (t >> 4) * 4;
    int col0 = (t & 15) * 8;

    float acc[4][8];
#pragma unroll
    for (int i = 0; i < 4; i++)
#pragma unroll
        for (int j = 0; j < 8; j++) acc[i][j] = 0.f;

    for (int k = 0; k < 128; k += 4) {
        float4 a[4];
#pragma unroll
        for (int i = 0; i < 4; i++) {
            int r = row0 + i; if (r >= N) r = N - 1;
            a[i] = load4f(&X[(size_t)r * 128 + k]);
        }
#pragma unroll
        for (int kk = 0; kk < 4; kk++) {
            float4 b0 = *(const float4*)&Wl[(k + kk) * 128 + col0];
            float4 b1 = *(const float4*)&Wl[(k + kk) * 128 + col0 + 4];
#pragma unroll
            for (int i = 0; i < 4; i++) {
                float av = (kk == 0) ? a[i].x : (kk == 1) ? a[i].y : (kk == 2) ? a[i].z : a[i].w;
                acc[i][0] += av * b0.x; acc[i][1] += av * b0.y;
                acc[i][2] += av * b0.z; acc[i][3] += av * b0.w;
                acc[i][4] += av * b1.x; acc[i][5] += av * b1.y;
                acc[i][6] += av * b1.z; acc[i][7] += av * b1.w;
            }
        }
    }
#pragma unroll
    for (int i = 0; i < 4; i++) {
        int r = row0 + i;
        if (r < N) {
            u16 o[8];
#pragma unroll
            for (int j = 0; j < 8; j++) o[j] = f2b(acc[i][j]);
            *(float4*)&Y[(size_t)r * 128 + col0] = *(float4*)o;
        }
    }
}

// ---------------- aggregation: one wave per node, bf16 rows ----------------
__global__ __launch_bounds__(256) void k_agg(const u16* __restrict__ XW,
                                             const float* __restrict__ dinv,
                                             const int* __restrict__ row_off,
                                             const int* __restrict__ csr_src,
                                             const float* __restrict__ bias,
                                             u16* __restrict__ OUT, int N, int do_relu) {
    int wave = (blockIdx.x * blockDim.x + threadIdx.x) >> 6;
    int lane = threadIdx.x & 63;
    if (wave >= N) return;
    int beg = row_off[wave], end = row_off[wave + 1];
    float din = dinv[wave];
    float ax = 0.f, ay = 0.f;
    int e = beg;
    for (; e + 1 < end; e += 2) {
        int s0 = csr_src[e], s1 = csr_src[e + 1];
        float d0 = dinv[s0], d1 = dinv[s1];
        ushort2 v0 = *(const ushort2*)&XW[(size_t)s0 * 128 + lane * 2];
        ushort2 v1 = *(const ushort2*)&XW[(size_t)s1 * 128 + lane * 2];
        ax += d0 * b2f(v0.x) + d1 * b2f(v1.x);
        ay += d0 * b2f(v0.y) + d1 * b2f(v1.y);
    }
    if (e < end) {
        int s0 = csr_src[e];
        float d0 = dinv[s0];
        ushort2 v0 = *(const ushort2*)&XW[(size_t)s0 * 128 + lane * 2];
        ax += d0 * b2f(v0.x);
        ay += d0 * b2f(v0.y);
    }
    ushort2 vs = *(const ushort2*)&XW[(size_t)wave * 128 + lane * 2];
    ax += din * b2f(vs.x);
    ay += din * b2f(vs.y);
    float ox = din * ax + bias[lane * 2], oy = din * ay + bias[lane * 2 + 1];
    if (do_relu) { ox = fmaxf(ox, 0.f); oy = fmaxf(oy, 0.f); }
    ushort2 o; o.x = f2b(ox); o.y = f2b(oy);
    *(ushort2*)&OUT[(size_t)wave * 128 + lane * 2] = o;
}

// ---------------- mean pool per graph (parallel, batch sorted) ----------------
__global__ __launch_bounds__(128) void k_pool_partial(const u16* __restrict__ H,
                                                      const int* __restrict__ batch, int N,
                                                      float* __restrict__ pooled) {
    int t = threadIdx.x;          // feature 0..127
    int chunk = (N + gridDim.x - 1) / gridDim.x;
    int beg = blockIdx.x * chunk;
    int end = beg + chunk; if (end > N) end = N;
    if (beg >= end) return;
    float acc = 0.f;
    int g = batch[beg];
    for (int nn = beg; nn < end; ++nn) {
        int gn = batch[nn];
        if (gn != g) {
            atomicAdd(&pooled[g * 128 + t], acc);
            acc = 0.f;
            g = gn;
        }
        acc += b2f(H[(size_t)nn * 128 + t]);
    }
    atomicAdd(&pooled[g * 128 + t], acc);
}

__global__ void k_pool_final(const int* __restrict__ batch, int N,
                             float* __restrict__ pooled) {
    int g = blockIdx.x;
    int t = threadIdx.x;
    __shared__ int sh[2];
    if (t == 0) {
        int lo = 0, hi = N;
        while (lo < hi) { int m = (lo + hi) >> 1; if (batch[m] < g) lo = m + 1; else hi = m; }
        sh[0] = lo;
        lo = 0; hi = N;
        while (lo < hi) { int m = (lo + hi) >> 1; if (batch[m] < g + 1) lo = m + 1; else hi = m; }
        sh[1] = lo;
    }
    __syncthreads();
    float cnt = (float)(sh[1] - sh[0]);
    if (cnt < 1.f) cnt = 1.f;
    pooled[g * 128 + t] /= cnt;
}

// ---------------- final MLP ----------------
__global__ void k_mlp(const float* __restrict__ pooled, const float* __restrict__ Wl1,
                      const float* __restrict__ bl1, const float* __restrict__ Wl2,
                      const float* __restrict__ bl2, float* __restrict__ out) {
    int g = blockIdx.x;
    int j = threadIdx.x;
    float acc = 0.f;
#pragma unroll 8
    for (int k = 0; k < 128; k++) acc += pooled[g * 128 + k] * Wl1[k * 64 + j];
    float h = fmaxf(acc + bl1[j], 0.f);
    float v = h * Wl2[j];
#pragma unroll
    for (int off = 32; off > 0; off >>= 1) v += __shfl_down(v, off);
    if (j == 0) out[g] = 1.f / (1.f + expf(-(v + bl2[0])));
}

// ---------------- launch ----------------
extern "C" void kernel_launch(void* const* d_in, const int* in_sizes, int n_in,
                              void* d_out, int out_size, void* d_ws, size_t ws_size,
                              hipStream_t stream) {
    const float* x    = (const float*)d_in[0];
    const int*   edge = (const int*)d_in[1];
    const int*   batch= (const int*)d_in[2];
    const float* W1   = (const float*)d_in[3];
    const float* b1   = (const float*)d_in[4];
    const float* W2   = (const float*)d_in[5];
    const float* b2   = (const float*)d_in[6];
    const float* Wl1  = (const float*)d_in[7];
    const float* bl1  = (const float*)d_in[8];
    const float* Wl2  = (const float*)d_in[9];
    const float* bl2  = (const float*)d_in[10];
    float* out = (float*)d_out;

    int N = in_sizes[0] / 128;
    int E = in_sizes[1] / 2;
    const int* src = edge;
    const int* dst = edge + E;

    char* ws = (char*)d_ws;
    size_t off = 0;
    auto alloc = [&](size_t bytes) { void* p = ws + off; off += (bytes + 511) & ~(size_t)511; return p; };
    float* dinv    = (float*)alloc((size_t)N * 4);
    u16*   bufA    = (u16*)alloc((size_t)N * 128 * 2);
    u16*   bufB    = (u16*)alloc((size_t)N * 128 * 2);
    int*   cnt     = (int*)alloc((size_t)N * 4);
    int*   cursor  = (int*)alloc((size_t)N * 4);
    int*   row_off = (int*)alloc((size_t)(N + 1) * 4);
    int*   csr_src = (int*)alloc((size_t)E * 4);
    int    nb      = (N + SCAN_B - 1) / SCAN_B;
    int*   partial = (int*)alloc((size_t)nb * 4);
    float* pooled  = (float*)alloc(64 * 128 * 4);

    hipMemsetAsync(cnt, 0, (size_t)N * 4, stream);
    hipMemsetAsync(cursor, 0, (size_t)N * 4, stream);
    hipMemsetAsync(pooled, 0, 64 * 128 * 4, stream);

    k_count<<<(E + 255) / 256, 256, 0, stream>>>(dst, E, cnt);
    k_dinv<<<(N + 255) / 256, 256, 0, stream>>>(cnt, dinv, N);
    k_scan1<<<nb, SCAN_B, 0, stream>>>(cnt, partial, N);
    k_scan2<<<1, 1024, 0, stream>>>(partial, nb);
    k_scan3<<<nb, SCAN_B, 0, stream>>>(cnt, partial, row_off, N, E);
    k_fill<<<(E + 255) / 256, 256, 0, stream>>>(src, dst, E, row_off, cursor, csr_src);

    k_gemm128<float><<<(N + 63) / 64, 256, 0, stream>>>(x, W1, bufA, N);
    k_agg<<<(N + 3) / 4, 256, 0, stream>>>(bufA, dinv, row_off, csr_src, b1, bufB, N, 1);
    k_gemm128<u16><<<(N + 63) / 64, 256, 0, stream>>>(bufB, W2, bufA, N);
    k_agg<<<(N + 3) / 4, 256, 0, stream>>>(bufA, dinv, row_off, csr_src, b2, bufB, N, 0);
    k_pool_partial<<<1024, 128, 0, stream>>>(bufB, batch, N, pooled);
    k_pool_final<<<64, 128, 0, stream>>>(batch, N, pooled);
    k_mlp<<<64, 64, 0, stream>>>(pooled, Wl1, bl1, Wl2, bl2, out);
}

// Round 4
// 405.976 us; speedup vs baseline: 2.5013x; 1.3589x over previous
//
#include <hip/hip_runtime.h>
#include <hip/hip_bf16.h>
#include <math.h>

typedef unsigned short u16;
typedef unsigned long long u64;
typedef __attribute__((ext_vector_type(8))) short bf16x8;
typedef __attribute__((ext_vector_type(4))) float f32x4;

__device__ __forceinline__ float b2f(u16 u) {
    union { unsigned int i; float f; } v; v.i = ((unsigned int)u) << 16; return v.f;
}
__device__ __forceinline__ u16 f2b(float f) {
    unsigned int i = __float_as_uint(f);
    unsigned int r = (i + 0x7FFFu + ((i >> 16) & 1u)) >> 16;
    return (u16)r;
}

// ---------------- degree / norm ----------------
__global__ void k_count(const int* __restrict__ dst, int E, int* __restrict__ cnt) {
    int i = blockIdx.x * blockDim.x + threadIdx.x;
    if (i < E) atomicAdd(&cnt[dst[i]], 1);
}

__global__ void k_dinv(const int* __restrict__ cnt, float* __restrict__ dinv, int N) {
    int i = blockIdx.x * blockDim.x + threadIdx.x;
    if (i < N) dinv[i] = rsqrtf((float)(cnt[i] + 1));  // +1 = self loop
}

// ---------------- scan (row offsets) ----------------
#define SCAN_B 256
__global__ void k_scan1(const int* __restrict__ cnt, int* __restrict__ partial, int N) {
    __shared__ int lds[SCAN_B];
    int i = blockIdx.x * SCAN_B + threadIdx.x;
    lds[threadIdx.x] = (i < N) ? cnt[i] : 0;
    __syncthreads();
    for (int s = SCAN_B / 2; s > 0; s >>= 1) {
        if (threadIdx.x < s) lds[threadIdx.x] += lds[threadIdx.x + s];
        __syncthreads();
    }
    if (threadIdx.x == 0) partial[blockIdx.x] = lds[0];
}

__global__ void k_scan2(int* __restrict__ partial, int nb) {
    __shared__ int lds[1024];
    int t = threadIdx.x;
    if (t < nb) lds[t] = partial[t];
    __syncthreads();
    if (t == 0) {
        int run = 0;
        for (int i = 0; i < nb; i++) { int v = lds[i]; lds[i] = run; run += v; }
    }
    __syncthreads();
    if (t < nb) partial[t] = lds[t];
}

__global__ void k_scan3(const int* __restrict__ cnt, const int* __restrict__ partial,
                        int* __restrict__ row_off, int N, int E) {
    __shared__ int lds[SCAN_B];
    int i = blockIdx.x * SCAN_B + threadIdx.x;
    int v = (i < N) ? cnt[i] : 0;
    int val = v;
    lds[threadIdx.x] = val;
    __syncthreads();
    for (int s = 1; s < SCAN_B; s <<= 1) {
        int add = (threadIdx.x >= s) ? lds[threadIdx.x - s] : 0;
        __syncthreads();
        val += add;
        lds[threadIdx.x] = val;
        __syncthreads();
    }
    if (i < N) row_off[i] = partial[blockIdx.x] + val - v;  // exclusive
    if (blockIdx.x == 0 && threadIdx.x == 0) row_off[N] = E;
}

// ---------------- bucketed CSR fill (kills scatter write-amp) ----------------
#define EPB 4096           // edges per pass-A block
#define BSHIFT 9           // 512 nodes per bucket
__global__ __launch_bounds__(256) void k_bucketA(const int* __restrict__ src,
                                                 const int* __restrict__ dst, int E,
                                                 const int* __restrict__ row_off,
                                                 int* __restrict__ bkcur,
                                                 u64* __restrict__ stage, int nbuck) {
    __shared__ int cntL[512];
    __shared__ int prefE[512];
    __shared__ int allocL[512];
    __shared__ int baseL[512];
    __shared__ u64 stageL[EPB];
    int t = threadIdx.x;
    int e0 = blockIdx.x * EPB;

    for (int i = t; i < 512; i += 256) cntL[i] = 0;
    __syncthreads();
#pragma unroll
    for (int j = 0; j < EPB / 256; j++) {
        int e = e0 + j * 256 + t;
        if (e < E) atomicAdd(&cntL[dst[e] >> BSHIFT], 1);
    }
    __syncthreads();
    // inclusive Hillis-Steele scan over 512 entries with 256 threads
    for (int i = t; i < 512; i += 256) prefE[i] = cntL[i];
    __syncthreads();
    for (int s = 1; s < 512; s <<= 1) {
        int v0 = (t >= s) ? prefE[t - s] : 0;
        int i1 = t + 256;
        int v1 = (i1 >= s) ? prefE[i1 - s] : 0;
        __syncthreads();
        prefE[t] += v0;
        prefE[i1] += v1;
        __syncthreads();
    }
    // make exclusive; init allocation cursors
    for (int i = t; i < 512; i += 256) {
        int ex = prefE[i] - cntL[i];
        prefE[i] = ex;
        allocL[i] = ex;
    }
    __syncthreads();
    // reserve global ranges (one atomic per non-empty bucket)
    for (int i = t; i < 512; i += 256) {
        if (i < nbuck && cntL[i] > 0)
            baseL[i] = row_off[i << BSHIFT] + atomicAdd(&bkcur[i], cntL[i]);
    }
    __syncthreads();
    // scatter edges into LDS, bucket-grouped
#pragma unroll
    for (int j = 0; j < EPB / 256; j++) {
        int e = e0 + j * 256 + t;
        if (e < E) {
            int d = dst[e];
            int b = d >> BSHIFT;
            int slot = atomicAdd(&allocL[b], 1);
            stageL[slot] = ((u64)(unsigned)d << 32) | (unsigned)src[e];
        }
    }
    __syncthreads();
    // coalesced write-out
    int tot = E - e0; if (tot > EPB) tot = EPB;
    for (int i = t; i < tot; i += 256) {
        u64 v = stageL[i];
        int b = (int)(v >> (32 + BSHIFT));
        stage[baseL[b] + (i - prefE[b])] = v;
    }
}

__global__ __launch_bounds__(256) void k_bucketB(const u64* __restrict__ stage,
                                                 const int* __restrict__ row_off,
                                                 int* __restrict__ cursor,
                                                 int* __restrict__ csr_src, int N) {
    int b = blockIdx.x;
    int t = threadIdx.x;
    int node_lo = b << BSHIFT;
    int node_hi = node_lo + (1 << BSHIFT); if (node_hi > N) node_hi = N;
    int rbeg = row_off[node_lo], rend = row_off[node_hi];
    for (int i = rbeg + t; i < rend; i += 256) {
        u64 v = stage[i];
        int d = (int)(v >> 32);
        int s = (int)(v & 0xFFFFFFFFu);
        int pos = row_off[d] + atomicAdd(&cursor[d], 1);
        csr_src[pos] = s;
    }
}

// ---------------- W transpose+bf16 prep: Wt[c][k] = bf16(W[k][c]) ----------------
__global__ void k_wt(const float* __restrict__ W1, const float* __restrict__ W2,
                     u16* __restrict__ Wt1, u16* __restrict__ Wt2) {
    const float* W = blockIdx.x ? W2 : W1;
    u16* Wt = blockIdx.x ? Wt2 : Wt1;
    int t = threadIdx.x;
    for (int i = t; i < 16384; i += 256) {
        int k = i >> 7, c = i & 127;
        Wt[c * 128 + k] = f2b(W[i]);
    }
}

// ---------------- MFMA GEMM: Y[N,128](bf16) = dinv[r] * (X[N,128] @ W) --------
// Wt is W^T in global bf16. Block: 256 thr = 4 waves, 64 rows. LDS holds Wt
// XOR-swizzled (byte ^= (row&7)<<4) to break the 256B-stride bank conflict.
template <typename TIN>
__global__ __launch_bounds__(256) void k_gemm_mfma(const TIN* __restrict__ X,
                                                   const u16* __restrict__ Wt,
                                                   const float* __restrict__ dinv,
                                                   u16* __restrict__ Y, int N) {
    __shared__ u16 WtL[128 * 128];
    int t = threadIdx.x;
    // copy Wt (32 KB) into LDS with swizzle
    {
        const char* gsrc = (const char*)Wt;
        char* lbase = (char*)WtL;
#pragma unroll
        for (int i = 0; i < 8; i++) {
            int idx16 = i * 256 + t;          // 16B units
            int byte = idx16 * 16;
            int row = byte >> 8;
            int swz = byte ^ ((row & 7) << 4);
            *(uint4*)(lbase + swz) = *(const uint4*)(gsrc + byte);
        }
    }
    __syncthreads();

    int wave = t >> 6, lane = t & 63;
    int r0w = blockIdx.x * 64 + wave * 16;    // this wave's 16 rows
    int lrow = lane & 15, lseg = lane >> 4;

    // load A fragments: 4 chunks of K=32
    bf16x8 a[4];
    {
        int row = r0w + lrow; if (row >= N) row = N - 1;
        if constexpr (sizeof(TIN) == 4) {
            const float* xp = (const float*)X + (size_t)row * 128 + lseg * 8;
#pragma unroll
            for (int j = 0; j < 4; j++) {
                float4 f0 = *(const float4*)(xp + j * 32);
                float4 f1 = *(const float4*)(xp + j * 32 + 4);
                bf16x8 v;
                v[0] = (short)f2b(f0.x); v[1] = (short)f2b(f0.y);
                v[2] = (short)f2b(f0.z); v[3] = (short)f2b(f0.w);
                v[4] = (short)f2b(f1.x); v[5] = (short)f2b(f1.y);
                v[6] = (short)f2b(f1.z); v[7] = (short)f2b(f1.w);
                a[j] = v;
            }
        } else {
            const u16* xp = (const u16*)X + (size_t)row * 128 + lseg * 8;
#pragma unroll
            for (int j = 0; j < 4; j++) a[j] = *(const bf16x8*)(xp + j * 32);
        }
    }

    // accumulate: 8 col-tiles x K=128
    f32x4 acc[8];
#pragma unroll
    for (int c = 0; c < 8; c++) acc[c] = (f32x4){0.f, 0.f, 0.f, 0.f};

    const char* lbase = (const char*)WtL;
#pragma unroll
    for (int c = 0; c < 8; c++) {
        int wrow = c * 16 + lrow;             // Wt row = W col
#pragma unroll
        for (int j = 0; j < 4; j++) {
            int byte = wrow * 256 + (j * 32 + lseg * 8) * 2;
            int swz = byte ^ ((wrow & 7) << 4);
            bf16x8 b = *(const bf16x8*)(lbase + swz);
            acc[c] = __builtin_amdgcn_mfma_f32_16x16x32_bf16(a[j], b, acc[c], 0, 0, 0);
        }
    }

    // epilogue: scale by dinv[row], store bf16
    float dv[4];
    int rowb = r0w + lseg * 4;
#pragma unroll
    for (int r = 0; r < 4; r++) {
        int row = rowb + r;
        dv[r] = (row < N) ? dinv[row] : 0.f;
    }
#pragma unroll
    for (int c = 0; c < 8; c++) {
#pragma unroll
        for (int r = 0; r < 4; r++) {
            int row = rowb + r;
            if (row < N) Y[(size_t)row * 128 + c * 16 + lrow] = f2b(acc[c][r] * dv[r]);
        }
    }
}

// ---------------- aggregation: one wave per node, prescaled bf16 rows --------
__global__ __launch_bounds__(256) void k_agg(const u16* __restrict__ Z,
                                             const float* __restrict__ dinv,
                                             const int* __restrict__ row_off,
                                             const int* __restrict__ csr_src,
                                             const float* __restrict__ bias,
                                             u16* __restrict__ OUT, int N, int do_relu) {
    int wave = (blockIdx.x * blockDim.x + threadIdx.x) >> 6;
    int lane = threadIdx.x & 63;
    if (wave >= N) return;
    int beg = row_off[wave], end = row_off[wave + 1];
    float din = dinv[wave];
    float ax = 0.f, ay = 0.f;
    int e = beg;
    for (; e + 3 < end; e += 4) {
        int s0 = csr_src[e], s1 = csr_src[e + 1], s2 = csr_src[e + 2], s3 = csr_src[e + 3];
        ushort2 v0 = *(const ushort2*)&Z[(size_t)s0 * 128 + lane * 2];
        ushort2 v1 = *(const ushort2*)&Z[(size_t)s1 * 128 + lane * 2];
        ushort2 v2 = *(const ushort2*)&Z[(size_t)s2 * 128 + lane * 2];
        ushort2 v3 = *(const ushort2*)&Z[(size_t)s3 * 128 + lane * 2];
        ax += (b2f(v0.x) + b2f(v1.x)) + (b2f(v2.x) + b2f(v3.x));
        ay += (b2f(v0.y) + b2f(v1.y)) + (b2f(v2.y) + b2f(v3.y));
    }
    for (; e < end; ++e) {
        int s0 = csr_src[e];
        ushort2 v0 = *(const ushort2*)&Z[(size_t)s0 * 128 + lane * 2];
        ax += b2f(v0.x); ay += b2f(v0.y);
    }
    ushort2 vs = *(const ushort2*)&Z[(size_t)wave * 128 + lane * 2];
    ax += b2f(vs.x); ay += b2f(vs.y);
    float2 bb = *(const float2*)&bias[lane * 2];
    float ox = din * ax + bb.x, oy = din * ay + bb.y;
    if (do_relu) { ox = fmaxf(ox, 0.f); oy = fmaxf(oy, 0.f); }
    ushort2 o; o.x = f2b(ox); o.y = f2b(oy);
    *(ushort2*)&OUT[(size_t)wave * 128 + lane * 2] = o;
}

// ---------------- mean pool per graph (parallel, batch sorted) ----------------
__global__ __launch_bounds__(128) void k_pool_partial(const u16* __restrict__ H,
                                                      const int* __restrict__ batch, int N,
                                                      float* __restrict__ pooled) {
    int t = threadIdx.x;
    int chunk = (N + gridDim.x - 1) / gridDim.x;
    int beg = blockIdx.x * chunk;
    int end = beg + chunk; if (end > N) end = N;
    if (beg >= end) return;
    float acc = 0.f;
    int g = batch[beg];
    for (int nn = beg; nn < end; ++nn) {
        int gn = batch[nn];
        if (gn != g) {
            atomicAdd(&pooled[g * 128 + t], acc);
            acc = 0.f;
            g = gn;
        }
        acc += b2f(H[(size_t)nn * 128 + t]);
    }
    atomicAdd(&pooled[g * 128 + t], acc);
}

__global__ void k_pool_final(const int* __restrict__ batch, int N,
                             float* __restrict__ pooled) {
    int g = blockIdx.x;
    int t = threadIdx.x;
    __shared__ int sh[2];
    if (t == 0) {
        int lo = 0, hi = N;
        while (lo < hi) { int m = (lo + hi) >> 1; if (batch[m] < g) lo = m + 1; else hi = m; }
        sh[0] = lo;
        lo = 0; hi = N;
        while (lo < hi) { int m = (lo + hi) >> 1; if (batch[m] < g + 1) lo = m + 1; else hi = m; }
        sh[1] = lo;
    }
    __syncthreads();
    float cnt = (float)(sh[1] - sh[0]);
    if (cnt < 1.f) cnt = 1.f;
    pooled[g * 128 + t] /= cnt;
}

// ---------------- final MLP ----------------
__global__ void k_mlp(const float* __restrict__ pooled, const float* __restrict__ Wl1,
                      const float* __restrict__ bl1, const float* __restrict__ Wl2,
                      const float* __restrict__ bl2, float* __restrict__ out) {
    int g = blockIdx.x;
    int j = threadIdx.x;
    float acc = 0.f;
#pragma unroll 8
    for (int k = 0; k < 128; k++) acc += pooled[g * 128 + k] * Wl1[k * 64 + j];
    float h = fmaxf(acc + bl1[j], 0.f);
    float v = h * Wl2[j];
#pragma unroll
    for (int off = 32; off > 0; off >>= 1) v += __shfl_down(v, off);
    if (j == 0) out[g] = 1.f / (1.f + expf(-(v + bl2[0])));
}

// ---------------- launch ----------------
extern "C" void kernel_launch(void* const* d_in, const int* in_sizes, int n_in,
                              void* d_out, int out_size, void* d_ws, size_t ws_size,
                              hipStream_t stream) {
    const float* x    = (const float*)d_in[0];
    const int*   edge = (const int*)d_in[1];
    const int*   batch= (const int*)d_in[2];
    const float* W1   = (const float*)d_in[3];
    const float* b1   = (const float*)d_in[4];
    const float* W2   = (const float*)d_in[5];
    const float* b2   = (const float*)d_in[6];
    const float* Wl1  = (const float*)d_in[7];
    const float* bl1  = (const float*)d_in[8];
    const float* Wl2  = (const float*)d_in[9];
    const float* bl2  = (const float*)d_in[10];
    float* out = (float*)d_out;

    int N = in_sizes[0] / 128;
    int E = in_sizes[1] / 2;
    const int* src = edge;
    const int* dst = edge + E;
    int nbuck = (N + (1 << BSHIFT) - 1) >> BSHIFT;

    char* ws = (char*)d_ws;
    size_t off = 0;
    auto alloc = [&](size_t bytes) { void* p = ws + off; off += (bytes + 511) & ~(size_t)511; return p; };
    float* dinv    = (float*)alloc((size_t)N * 4);
    u16*   bufA    = (u16*)alloc((size_t)N * 128 * 2);
    u16*   bufB    = (u16*)alloc((size_t)N * 128 * 2);
    int*   cnt     = (int*)alloc((size_t)N * 4);
    int*   cursor  = (int*)alloc((size_t)N * 4);
    int*   row_off = (int*)alloc((size_t)(N + 1) * 4);
    int*   csr_src = (int*)alloc((size_t)E * 4);
    u64*   stage   = (u64*)alloc((size_t)E * 8);
    int*   bkcur   = (int*)alloc((size_t)nbuck * 4);
    int    nb      = (N + SCAN_B - 1) / SCAN_B;
    int*   partial = (int*)alloc((size_t)nb * 4);
    float* pooled  = (float*)alloc(64 * 128 * 4);
    u16*   Wt1     = (u16*)alloc(128 * 128 * 2);
    u16*   Wt2     = (u16*)alloc(128 * 128 * 2);

    hipMemsetAsync(cnt, 0, (size_t)N * 4, stream);
    hipMemsetAsync(cursor, 0, (size_t)N * 4, stream);
    hipMemsetAsync(bkcur, 0, (size_t)nbuck * 4, stream);
    hipMemsetAsync(pooled, 0, 64 * 128 * 4, stream);

    k_count<<<(E + 255) / 256, 256, 0, stream>>>(dst, E, cnt);
    k_dinv<<<(N + 255) / 256, 256, 0, stream>>>(cnt, dinv, N);
    k_scan1<<<nb, SCAN_B, 0, stream>>>(cnt, partial, N);
    k_scan2<<<1, 1024, 0, stream>>>(partial, nb);
    k_scan3<<<nb, SCAN_B, 0, stream>>>(cnt, partial, row_off, N, E);
    k_wt<<<2, 256, 0, stream>>>(W1, W2, Wt1, Wt2);
    k_bucketA<<<(E + EPB - 1) / EPB, 256, 0, stream>>>(src, dst, E, row_off, bkcur, stage, nbuck);
    k_bucketB<<<nbuck, 256, 0, stream>>>(stage, row_off, cursor, csr_src, N);

    k_gemm_mfma<float><<<(N + 63) / 64, 256, 0, stream>>>(x, Wt1, dinv, bufA, N);
    k_agg<<<(N + 3) / 4, 256, 0, stream>>>(bufA, dinv, row_off, csr_src, b1, bufB, N, 1);
    k_gemm_mfma<u16><<<(N + 63) / 64, 256, 0, stream>>>(bufB, Wt2, dinv, bufA, N);
    k_agg<<<(N + 3) / 4, 256, 0, stream>>>(bufA, dinv, row_off, csr_src, b2, bufB, N, 0);
    k_pool_partial<<<1024, 128, 0, stream>>>(bufB, batch, N, pooled);
    k_pool_final<<<64, 128, 0, stream>>>(batch, N, pooled);
    k_mlp<<<64, 64, 0, stream>>>(pooled, Wl1, bl1, Wl2, bl2, out);
}

// Round 5
// 319.960 us; speedup vs baseline: 3.1737x; 1.2688x over previous
//
#include <hip/hip_runtime.h>
#include <hip/hip_bf16.h>
#include <math.h>

typedef unsigned short u16;
typedef unsigned char u8;
typedef unsigned int u32;
typedef unsigned long long u64;
typedef __attribute__((ext_vector_type(8))) short bf16x8;
typedef __attribute__((ext_vector_type(4))) float f32x4;
typedef __attribute__((ext_vector_type(2))) float f32x2;

__device__ __forceinline__ float b2f(u16 u) {
    union { unsigned int i; float f; } v; v.i = ((unsigned int)u) << 16; return v.f;
}
__device__ __forceinline__ u16 f2b(float f) {
    unsigned int i = __float_as_uint(f);
    unsigned int r = (i + 0x7FFFu + ((i >> 16) & 1u)) >> 16;
    return (u16)r;
}
// fp8 e4m3 HW conversions (gfx950 OCP): 2 values per instruction
__device__ __forceinline__ f32x2 fp8x2_to_f32(u32 two_bytes) {
    return __builtin_amdgcn_cvt_pk_f32_fp8((int)two_bytes, false);
}
__device__ __forceinline__ u32 f32x2_to_fp8(float a, float b) {
    return (u32)__builtin_amdgcn_cvt_pk_fp8_f32(a, b, 0, false);
}

#define BSHIFT 9            // 512 nodes per bucket
#define EPB 4096            // edges per bucketA block
#define BH_CHUNK 16384      // edges per bhist block
#define SRC_MASK 0x1FFFFu   // 17 bits (N < 131072)

// ---------------- bucket histogram (196 buckets) ----------------
__global__ __launch_bounds__(256) void k_bhist(const int* __restrict__ dst, int E,
                                               int* __restrict__ bcnt, int nbuck) {
    __shared__ int h[256];
    int t = threadIdx.x;
    h[t] = 0;
    __syncthreads();
    int e0 = blockIdx.x * BH_CHUNK;
    int e1 = e0 + BH_CHUNK; if (e1 > E) e1 = E;
    for (int i = e0 + t; i < e1; i += 256) atomicAdd(&h[dst[i] >> BSHIFT], 1);
    __syncthreads();
    if (t < nbuck && h[t] > 0) atomicAdd(&bcnt[t], h[t]);
}

// ---------------- bucket base scan (exclusive, <=256 entries) ----------------
__global__ __launch_bounds__(256) void k_bscan(const int* __restrict__ bcnt,
                                               int* __restrict__ bbase,
                                               int* __restrict__ row_off,
                                               int nbuck, int N, int E) {
    __shared__ int lds[256];
    int t = threadIdx.x;
    int mine = (t < nbuck) ? bcnt[t] : 0;
    lds[t] = mine;
    __syncthreads();
    int val = mine;
    for (int s = 1; s < 256; s <<= 1) {
        int add = (t >= s) ? lds[t - s] : 0;
        __syncthreads();
        val += add;
        lds[t] = val;
        __syncthreads();
    }
    if (t < nbuck) bbase[t] = val - mine;
    if (t == nbuck - 1) bbase[nbuck] = val;
    if (t == 0) row_off[N] = E;
}

// ---------------- bucketA: stage edges grouped by dst-bucket ----------------
__global__ __launch_bounds__(256) void k_bucketA(const int* __restrict__ src,
                                                 const int* __restrict__ dst, int E,
                                                 const int* __restrict__ bbase,
                                                 int* __restrict__ bkcur,
                                                 u32* __restrict__ stage, int nbuck) {
    __shared__ int cntL[512];
    __shared__ int prefE[512];
    __shared__ int allocL[512];
    __shared__ int baseL[512];
    __shared__ u64 stageL[EPB];
    int t = threadIdx.x;
    int e0 = blockIdx.x * EPB;

    for (int i = t; i < 512; i += 256) cntL[i] = 0;
    __syncthreads();
#pragma unroll
    for (int j = 0; j < EPB / 256; j++) {
        int e = e0 + j * 256 + t;
        if (e < E) atomicAdd(&cntL[dst[e] >> BSHIFT], 1);
    }
    __syncthreads();
    for (int i = t; i < 512; i += 256) prefE[i] = cntL[i];
    __syncthreads();
    for (int s = 1; s < 512; s <<= 1) {
        int v0 = (t >= s) ? prefE[t - s] : 0;
        int i1 = t + 256;
        int v1 = (i1 >= s) ? prefE[i1 - s] : 0;
        __syncthreads();
        prefE[t] += v0;
        prefE[i1] += v1;
        __syncthreads();
    }
    for (int i = t; i < 512; i += 256) {
        int ex = prefE[i] - cntL[i];
        prefE[i] = ex;
        allocL[i] = ex;
    }
    __syncthreads();
    for (int i = t; i < 512; i += 256) {
        if (i < nbuck && cntL[i] > 0)
            baseL[i] = bbase[i] + atomicAdd(&bkcur[i], cntL[i]);
    }
    __syncthreads();
#pragma unroll
    for (int j = 0; j < EPB / 256; j++) {
        int e = e0 + j * 256 + t;
        if (e < E) {
            int d = dst[e];
            int b = d >> BSHIFT;
            int slot = atomicAdd(&allocL[b], 1);
            stageL[slot] = ((u64)(unsigned)d << 32) | (unsigned)src[e];
        }
    }
    __syncthreads();
    int tot = E - e0; if (tot > EPB) tot = EPB;
    for (int i = t; i < tot; i += 256) {
        u64 v = stageL[i];
        int b = (int)(v >> (32 + BSHIFT));
        u32 d9 = (u32)((v >> 32) & 511u);
        u32 packed = (d9 << 17) | ((u32)v & SRC_MASK);
        stage[baseL[b] + (i - prefE[b])] = packed;
    }
}

// ------- bucketB: local hist+scan -> row_off, dinv, csr placement -------
__global__ __launch_bounds__(256) void k_bucketB(const u32* __restrict__ stage,
                                                 const int* __restrict__ bbase,
                                                 int* __restrict__ csr_src,
                                                 int* __restrict__ row_off,
                                                 float* __restrict__ dinv, int N) {
    __shared__ int hist[512];
    __shared__ int pref[512];
    __shared__ int cur[512];
    int b = blockIdx.x, t = threadIdx.x;
    int node_lo = b << BSHIFT;
    int nloc = N - node_lo; if (nloc > 512) nloc = 512;
    int rbeg = bbase[b], rend = bbase[b + 1];

    for (int i = t; i < 512; i += 256) hist[i] = 0;
    __syncthreads();
    for (int i = rbeg + t; i < rend; i += 256) atomicAdd(&hist[stage[i] >> 17], 1);
    __syncthreads();
    for (int i = t; i < 512; i += 256) pref[i] = hist[i];
    __syncthreads();
    for (int s = 1; s < 512; s <<= 1) {
        int v0 = (t >= s) ? pref[t - s] : 0;
        int i1 = t + 256;
        int v1 = (i1 >= s) ? pref[i1 - s] : 0;
        __syncthreads();
        pref[t] += v0;
        pref[i1] += v1;
        __syncthreads();
    }
    for (int i = t; i < 512; i += 256) {
        int ex = pref[i] - hist[i];
        cur[i] = rbeg + ex;
        if (i < nloc) {
            row_off[node_lo + i] = rbeg + ex;
            dinv[node_lo + i] = rsqrtf((float)(hist[i] + 1));  // +1 self loop
        }
    }
    __syncthreads();
    for (int i = rbeg + t; i < rend; i += 256) {
        u32 v = stage[i];
        int pos = atomicAdd(&cur[v >> 17], 1);
        csr_src[pos] = (int)(v & SRC_MASK);
    }
}

// ---------------- W transpose+bf16 prep: Wt[c][k] = bf16(W[k][c]) ------------
__global__ void k_wt(const float* __restrict__ W1, const float* __restrict__ W2,
                     u16* __restrict__ Wt1, u16* __restrict__ Wt2) {
    const float* W = blockIdx.x ? W2 : W1;
    u16* Wt = blockIdx.x ? Wt2 : Wt1;
    int t = threadIdx.x;
    for (int i = t; i < 16384; i += 256) {
        int k = i >> 7, c = i & 127;
        Wt[c * 128 + k] = f2b(W[i]);
    }
}

// -------- MFMA GEMM: Z[N,128](fp8) = dinv[r] * (X[N,128] @ W) ----------------
template <typename TIN>
__global__ __launch_bounds__(256) void k_gemm_mfma(const TIN* __restrict__ X,
                                                   const u16* __restrict__ Wt,
                                                   const float* __restrict__ dinv,
                                                   u8* __restrict__ Y, int N) {
    __shared__ u16 WtL[128 * 128];
    __shared__ u8 YL[4][16 * 128];
    int t = threadIdx.x;
    {
        const char* gsrc = (const char*)Wt;
        char* lbase = (char*)WtL;
#pragma unroll
        for (int i = 0; i < 8; i++) {
            int byte = (i * 256 + t) * 16;
            int row = byte >> 8;
            int swz = byte ^ ((row & 7) << 4);
            *(uint4*)(lbase + swz) = *(const uint4*)(gsrc + byte);
        }
    }
    __syncthreads();

    int wave = t >> 6, lane = t & 63;
    int r0w = blockIdx.x * 64 + wave * 16;
    int lrow = lane & 15, lseg = lane >> 4;

    bf16x8 a[4];
    {
        int row = r0w + lrow; if (row >= N) row = N - 1;
        if constexpr (sizeof(TIN) == 4) {
            const float* xp = (const float*)X + (size_t)row * 128 + lseg * 8;
#pragma unroll
            for (int j = 0; j < 4; j++) {
                float4 f0 = *(const float4*)(xp + j * 32);
                float4 f1 = *(const float4*)(xp + j * 32 + 4);
                bf16x8 v;
                v[0] = (short)f2b(f0.x); v[1] = (short)f2b(f0.y);
                v[2] = (short)f2b(f0.z); v[3] = (short)f2b(f0.w);
                v[4] = (short)f2b(f1.x); v[5] = (short)f2b(f1.y);
                v[6] = (short)f2b(f1.z); v[7] = (short)f2b(f1.w);
                a[j] = v;
            }
        } else {
            const u16* xp = (const u16*)X + (size_t)row * 128 + lseg * 8;
#pragma unroll
            for (int j = 0; j < 4; j++) a[j] = *(const bf16x8*)(xp + j * 32);
        }
    }

    f32x4 acc[8];
#pragma unroll
    for (int c = 0; c < 8; c++) acc[c] = (f32x4){0.f, 0.f, 0.f, 0.f};

    const char* lbase = (const char*)WtL;
#pragma unroll
    for (int c = 0; c < 8; c++) {
        int wrow = c * 16 + lrow;
#pragma unroll
        for (int j = 0; j < 4; j++) {
            int byte = wrow * 256 + (j * 32 + lseg * 8) * 2;
            int swz = byte ^ ((wrow & 7) << 4);
            bf16x8 bf = *(const bf16x8*)(lbase + swz);
            acc[c] = __builtin_amdgcn_mfma_f32_16x16x32_bf16(a[j], bf, acc[c], 0, 0, 0);
        }
    }

    // epilogue: scale by dinv, convert fp8, repack via LDS, coalesced store
    float dv[4];
    int rowb = r0w + lseg * 4;
#pragma unroll
    for (int r = 0; r < 4; r++) {
        int row = rowb + r;
        dv[r] = (row < N) ? dinv[row] : 0.f;
    }
    u8* yw = &YL[wave][0];
#pragma unroll
    for (int c = 0; c < 8; c++) {
        u32 p01 = f32x2_to_fp8(acc[c][0] * dv[0], acc[c][1] * dv[1]);
        u32 p23 = f32x2_to_fp8(acc[c][2] * dv[2], acc[c][3] * dv[3]);
        int base = (lseg * 4) * 128 + c * 16 + lrow;
        yw[base]           = (u8)p01;
        yw[base + 128]     = (u8)(p01 >> 8);
        yw[base + 256]     = (u8)p23;
        yw[base + 384]     = (u8)(p23 >> 8);
    }
#pragma unroll
    for (int k = 0; k < 2; k++) {
        int idx = lane + 64 * k;
        int row = idx >> 3;
        int seg = idx & 7;
        int grow = r0w + row;
        uint4 v = *(const uint4*)&yw[row * 128 + seg * 16];
        if (grow < N) *(uint4*)&Y[(size_t)grow * 128 + seg * 16] = v;
    }
}

// -------- aggregation: one wave per node, fp8 prescaled rows -> bf16 ---------
__global__ __launch_bounds__(256) void k_agg(const u8* __restrict__ Z,
                                             const float* __restrict__ dinv,
                                             const int* __restrict__ row_off,
                                             const int* __restrict__ csr_src,
                                             const float* __restrict__ bias,
                                             u16* __restrict__ OUT, int N, int do_relu) {
    int wave = (blockIdx.x * blockDim.x + threadIdx.x) >> 6;
    int lane = threadIdx.x & 63;
    if (wave >= N) return;
    int beg = row_off[wave], end = row_off[wave + 1];
    float din = dinv[wave];
    float ax = 0.f, ay = 0.f;
    int e = beg;
    // head: align e to 4 for int4 csr loads
    while (e < end && (e & 3)) {
        int s = csr_src[e];
        f32x2 f = fp8x2_to_f32(*(const u16*)&Z[(size_t)s * 128 + lane * 2]);
        ax += f.x; ay += f.y;
        ++e;
    }
    for (; e + 3 < end; e += 4) {
        int4 s4 = *(const int4*)&csr_src[e];
        f32x2 f0 = fp8x2_to_f32(*(const u16*)&Z[(size_t)s4.x * 128 + lane * 2]);
        f32x2 f1 = fp8x2_to_f32(*(const u16*)&Z[(size_t)s4.y * 128 + lane * 2]);
        f32x2 f2 = fp8x2_to_f32(*(const u16*)&Z[(size_t)s4.z * 128 + lane * 2]);
        f32x2 f3 = fp8x2_to_f32(*(const u16*)&Z[(size_t)s4.w * 128 + lane * 2]);
        ax += (f0.x + f1.x) + (f2.x + f3.x);
        ay += (f0.y + f1.y) + (f2.y + f3.y);
    }
    for (; e < end; ++e) {
        int s = csr_src[e];
        f32x2 f = fp8x2_to_f32(*(const u16*)&Z[(size_t)s * 128 + lane * 2]);
        ax += f.x; ay += f.y;
    }
    // self loop (Z already prescaled by dinv)
    {
        f32x2 f = fp8x2_to_f32(*(const u16*)&Z[(size_t)wave * 128 + lane * 2]);
        ax += f.x; ay += f.y;
    }
    float2 bb = *(const float2*)&bias[lane * 2];
    float ox = din * ax + bb.x, oy = din * ay + bb.y;
    if (do_relu) { ox = fmaxf(ox, 0.f); oy = fmaxf(oy, 0.f); }
    ushort2 o; o.x = f2b(ox); o.y = f2b(oy);
    *(ushort2*)&OUT[(size_t)wave * 128 + lane * 2] = o;
}

// ---------------- mean pool per graph (parallel, batch sorted) ----------------
__global__ __launch_bounds__(128) void k_pool_partial(const u16* __restrict__ H,
                                                      const int* __restrict__ batch, int N,
                                                      float* __restrict__ pooled) {
    int t = threadIdx.x;
    int chunk = (N + gridDim.x - 1) / gridDim.x;
    int beg = blockIdx.x * chunk;
    int end = beg + chunk; if (end > N) end = N;
    if (beg >= end) return;
    float acc = 0.f;
    int g = batch[beg];
    for (int nn = beg; nn < end; ++nn) {
        int gn = batch[nn];
        if (gn != g) {
            atomicAdd(&pooled[g * 128 + t], acc);
            acc = 0.f;
            g = gn;
        }
        acc += b2f(H[(size_t)nn * 128 + t]);
    }
    atomicAdd(&pooled[g * 128 + t], acc);
}

__global__ void k_pool_final(const int* __restrict__ batch, int N,
                             float* __restrict__ pooled) {
    int g = blockIdx.x;
    int t = threadIdx.x;
    __shared__ int sh[2];
    if (t == 0) {
        int lo = 0, hi = N;
        while (lo < hi) { int m = (lo + hi) >> 1; if (batch[m] < g) lo = m + 1; else hi = m; }
        sh[0] = lo;
        lo = 0; hi = N;
        while (lo < hi) { int m = (lo + hi) >> 1; if (batch[m] < g + 1) lo = m + 1; else hi = m; }
        sh[1] = lo;
    }
    __syncthreads();
    float cnt = (float)(sh[1] - sh[0]);
    if (cnt < 1.f) cnt = 1.f;
    pooled[g * 128 + t] /= cnt;
}

// ---------------- final MLP ----------------
__global__ void k_mlp(const float* __restrict__ pooled, const float* __restrict__ Wl1,
                      const float* __restrict__ bl1, const float* __restrict__ Wl2,
                      const float* __restrict__ bl2, float* __restrict__ out) {
    int g = blockIdx.x;
    int j = threadIdx.x;
    float acc = 0.f;
#pragma unroll 8
    for (int k = 0; k < 128; k++) acc += pooled[g * 128 + k] * Wl1[k * 64 + j];
    float h = fmaxf(acc + bl1[j], 0.f);
    float v = h * Wl2[j];
#pragma unroll
    for (int off = 32; off > 0; off >>= 1) v += __shfl_down(v, off);
    if (j == 0) out[g] = 1.f / (1.f + expf(-(v + bl2[0])));
}

// ---------------- launch ----------------
extern "C" void kernel_launch(void* const* d_in, const int* in_sizes, int n_in,
                              void* d_out, int out_size, void* d_ws, size_t ws_size,
                              hipStream_t stream) {
    const float* x    = (const float*)d_in[0];
    const int*   edge = (const int*)d_in[1];
    const int*   batch= (const int*)d_in[2];
    const float* W1   = (const float*)d_in[3];
    const float* b1   = (const float*)d_in[4];
    const float* W2   = (const float*)d_in[5];
    const float* b2   = (const float*)d_in[6];
    const float* Wl1  = (const float*)d_in[7];
    const float* bl1  = (const float*)d_in[8];
    const float* Wl2  = (const float*)d_in[9];
    const float* bl2  = (const float*)d_in[10];
    float* out = (float*)d_out;

    int N = in_sizes[0] / 128;
    int E = in_sizes[1] / 2;
    const int* src = edge;
    const int* dst = edge + E;
    int nbuck = (N + (1 << BSHIFT) - 1) >> BSHIFT;

    char* ws = (char*)d_ws;
    size_t off = 0;
    auto alloc = [&](size_t bytes) { void* p = ws + off; off += (bytes + 511) & ~(size_t)511; return p; };
    float* dinv    = (float*)alloc((size_t)N * 4);
    u8*    Z       = (u8*)alloc((size_t)N * 128);        // fp8 gather buffer
    u16*   H       = (u16*)alloc((size_t)N * 128 * 2);   // bf16 agg output
    int*   row_off = (int*)alloc((size_t)(N + 1) * 4);
    int*   csr_src = (int*)alloc((size_t)E * 4);
    u32*   stage   = (u32*)alloc((size_t)E * 4);
    int*   bcnt    = (int*)alloc(256 * 4);
    int*   bbase   = (int*)alloc(260 * 4);
    int*   bkcur   = (int*)alloc(256 * 4);
    float* pooled  = (float*)alloc(64 * 128 * 4);
    u16*   Wt1     = (u16*)alloc(128 * 128 * 2);
    u16*   Wt2     = (u16*)alloc(128 * 128 * 2);

    hipMemsetAsync(bcnt, 0, 256 * 4, stream);
    hipMemsetAsync(bkcur, 0, 256 * 4, stream);
    hipMemsetAsync(pooled, 0, 64 * 128 * 4, stream);

    k_bhist<<<(E + BH_CHUNK - 1) / BH_CHUNK, 256, 0, stream>>>(dst, E, bcnt, nbuck);
    k_bscan<<<1, 256, 0, stream>>>(bcnt, bbase, row_off, nbuck, N, E);
    k_wt<<<2, 256, 0, stream>>>(W1, W2, Wt1, Wt2);
    k_bucketA<<<(E + EPB - 1) / EPB, 256, 0, stream>>>(src, dst, E, bbase, bkcur, stage, nbuck);
    k_bucketB<<<nbuck, 256, 0, stream>>>(stage, bbase, csr_src, row_off, dinv, N);

    k_gemm_mfma<float><<<(N + 63) / 64, 256, 0, stream>>>(x, Wt1, dinv, Z, N);
    k_agg<<<(N + 3) / 4, 256, 0, stream>>>(Z, dinv, row_off, csr_src, b1, H, N, 1);
    k_gemm_mfma<u16><<<(N + 63) / 64, 256, 0, stream>>>(H, Wt2, dinv, Z, N);
    k_agg<<<(N + 3) / 4, 256, 0, stream>>>(Z, dinv, row_off, csr_src, b2, H, N, 0);
    k_pool_partial<<<1024, 128, 0, stream>>>(H, batch, N, pooled);
    k_pool_final<<<64, 128, 0, stream>>>(batch, N, pooled);
    k_mlp<<<64, 64, 0, stream>>>(pooled, Wl1, bl1, Wl2, bl2, out);
}

// Round 6
// 279.992 us; speedup vs baseline: 3.6268x; 1.1427x over previous
//
#include <hip/hip_runtime.h>
#include <hip/hip_bf16.h>
#include <math.h>

typedef unsigned short u16;
typedef unsigned char u8;
typedef unsigned int u32;
typedef unsigned long long u64;
typedef __attribute__((ext_vector_type(8))) short bf16x8;
typedef __attribute__((ext_vector_type(4))) float f32x4;
typedef __attribute__((ext_vector_type(2))) float f32x2;

__device__ __forceinline__ float b2f(u16 u) {
    union { unsigned int i; float f; } v; v.i = ((unsigned int)u) << 16; return v.f;
}
__device__ __forceinline__ u16 f2b(float f) {
    unsigned int i = __float_as_uint(f);
    unsigned int r = (i + 0x7FFFu + ((i >> 16) & 1u)) >> 16;
    return (u16)r;
}
// fp8 e4m3 HW conversions (gfx950 OCP): 2 values per instruction
__device__ __forceinline__ f32x2 fp8x2_lo(u32 w) { return __builtin_amdgcn_cvt_pk_f32_fp8((int)w, false); }
__device__ __forceinline__ f32x2 fp8x2_hi(u32 w) { return __builtin_amdgcn_cvt_pk_f32_fp8((int)w, true); }
__device__ __forceinline__ u32 f32x2_to_fp8(float a, float b) {
    return (u32)__builtin_amdgcn_cvt_pk_fp8_f32(a, b, 0, false);
}

#define BSHIFT 9            // 512 nodes per bucket
#define EPB 4096            // edges per bucketA block
#define BH_CHUNK 16384      // edges per bhist block
#define SRC_MASK 0x1FFFFu   // 17 bits (N < 131072)

// ---------------- bucket histogram ----------------
__global__ __launch_bounds__(256) void k_bhist(const int* __restrict__ dst, int E,
                                               int* __restrict__ bcnt, int nbuck) {
    __shared__ int h[256];
    int t = threadIdx.x;
    h[t] = 0;
    __syncthreads();
    int e0 = blockIdx.x * BH_CHUNK;
    int e1 = e0 + BH_CHUNK; if (e1 > E) e1 = E;
    for (int i = e0 + t; i < e1; i += 256) atomicAdd(&h[dst[i] >> BSHIFT], 1);
    __syncthreads();
    if (t < nbuck && h[t] > 0) atomicAdd(&bcnt[t], h[t]);
}

// ---------------- bucket base scan ----------------
__global__ __launch_bounds__(256) void k_bscan(const int* __restrict__ bcnt,
                                               int* __restrict__ bbase,
                                               int* __restrict__ row_off,
                                               int nbuck, int N, int E) {
    __shared__ int lds[256];
    int t = threadIdx.x;
    int mine = (t < nbuck) ? bcnt[t] : 0;
    lds[t] = mine;
    __syncthreads();
    int val = mine;
    for (int s = 1; s < 256; s <<= 1) {
        int add = (t >= s) ? lds[t - s] : 0;
        __syncthreads();
        val += add;
        lds[t] = val;
        __syncthreads();
    }
    if (t < nbuck) bbase[t] = val - mine;
    if (t == nbuck - 1) bbase[nbuck] = val;
    if (t == 0) row_off[N] = E;
}

// ---------------- bucketA: stage edges grouped by dst-bucket ----------------
__global__ __launch_bounds__(256) void k_bucketA(const int* __restrict__ src,
                                                 const int* __restrict__ dst, int E,
                                                 const int* __restrict__ bbase,
                                                 int* __restrict__ bkcur,
                                                 u32* __restrict__ stage, int nbuck) {
    __shared__ int cntL[512];
    __shared__ int prefE[512];
    __shared__ int allocL[512];
    __shared__ int baseL[512];
    __shared__ u64 stageL[EPB];
    int t = threadIdx.x;
    int e0 = blockIdx.x * EPB;

    for (int i = t; i < 512; i += 256) cntL[i] = 0;
    __syncthreads();
#pragma unroll
    for (int j = 0; j < EPB / 256; j++) {
        int e = e0 + j * 256 + t;
        if (e < E) atomicAdd(&cntL[dst[e] >> BSHIFT], 1);
    }
    __syncthreads();
    for (int i = t; i < 512; i += 256) prefE[i] = cntL[i];
    __syncthreads();
    for (int s = 1; s < 512; s <<= 1) {
        int v0 = (t >= s) ? prefE[t - s] : 0;
        int i1 = t + 256;
        int v1 = (i1 >= s) ? prefE[i1 - s] : 0;
        __syncthreads();
        prefE[t] += v0;
        prefE[i1] += v1;
        __syncthreads();
    }
    for (int i = t; i < 512; i += 256) {
        int ex = prefE[i] - cntL[i];
        prefE[i] = ex;
        allocL[i] = ex;
    }
    __syncthreads();
    for (int i = t; i < 512; i += 256) {
        if (i < nbuck && cntL[i] > 0)
            baseL[i] = bbase[i] + atomicAdd(&bkcur[i], cntL[i]);
    }
    __syncthreads();
#pragma unroll
    for (int j = 0; j < EPB / 256; j++) {
        int e = e0 + j * 256 + t;
        if (e < E) {
            int d = dst[e];
            int b = d >> BSHIFT;
            int slot = atomicAdd(&allocL[b], 1);
            stageL[slot] = ((u64)(unsigned)d << 32) | (unsigned)src[e];
        }
    }
    __syncthreads();
    int tot = E - e0; if (tot > EPB) tot = EPB;
    for (int i = t; i < tot; i += 256) {
        u64 v = stageL[i];
        int b = (int)(v >> (32 + BSHIFT));
        u32 d9 = (u32)((v >> 32) & 511u);
        u32 packed = (d9 << 17) | ((u32)v & SRC_MASK);
        stage[baseL[b] + (i - prefE[b])] = packed;
    }
}

// ------- bucketB: local hist+scan -> row_off, dinv, csr placement -------
__global__ __launch_bounds__(256) void k_bucketB(const u32* __restrict__ stage,
                                                 const int* __restrict__ bbase,
                                                 int* __restrict__ csr_src,
                                                 int* __restrict__ row_off,
                                                 float* __restrict__ dinv, int N) {
    __shared__ int hist[512];
    __shared__ int pref[512];
    __shared__ int cur[512];
    int b = blockIdx.x, t = threadIdx.x;
    int node_lo = b << BSHIFT;
    int nloc = N - node_lo; if (nloc > 512) nloc = 512;
    int rbeg = bbase[b], rend = bbase[b + 1];

    for (int i = t; i < 512; i += 256) hist[i] = 0;
    __syncthreads();
    for (int i = rbeg + t; i < rend; i += 256) atomicAdd(&hist[stage[i] >> 17], 1);
    __syncthreads();
    for (int i = t; i < 512; i += 256) pref[i] = hist[i];
    __syncthreads();
    for (int s = 1; s < 512; s <<= 1) {
        int v0 = (t >= s) ? pref[t - s] : 0;
        int i1 = t + 256;
        int v1 = (i1 >= s) ? pref[i1 - s] : 0;
        __syncthreads();
        pref[t] += v0;
        pref[i1] += v1;
        __syncthreads();
    }
    for (int i = t; i < 512; i += 256) {
        int ex = pref[i] - hist[i];
        cur[i] = rbeg + ex;
        if (i < nloc) {
            row_off[node_lo + i] = rbeg + ex;
            dinv[node_lo + i] = rsqrtf((float)(hist[i] + 1));  // +1 self loop
        }
    }
    __syncthreads();
    for (int i = rbeg + t; i < rend; i += 256) {
        u32 v = stage[i];
        int pos = atomicAdd(&cur[v >> 17], 1);
        csr_src[pos] = (int)(v & SRC_MASK);
    }
}

// ---------------- W transpose+bf16 prep ----------------
__global__ void k_wt(const float* __restrict__ W1, const float* __restrict__ W2,
                     u16* __restrict__ Wt1, u16* __restrict__ Wt2) {
    const float* W = blockIdx.x ? W2 : W1;
    u16* Wt = blockIdx.x ? Wt2 : Wt1;
    int t = threadIdx.x;
    for (int i = t; i < 16384; i += 256) {
        int k = i >> 7, c = i & 127;
        Wt[c * 128 + k] = f2b(W[i]);
    }
}

// -------- MFMA GEMM: Z[N,128](fp8) = dinv[r] * (X[N,128] @ W) ----------------
template <typename TIN>
__global__ __launch_bounds__(256) void k_gemm_mfma(const TIN* __restrict__ X,
                                                   const u16* __restrict__ Wt,
                                                   const float* __restrict__ dinv,
                                                   u8* __restrict__ Y, int N) {
    __shared__ u16 WtL[128 * 128];
    __shared__ u8 YL[4][16 * 128];
    int t = threadIdx.x;
    {
        const char* gsrc = (const char*)Wt;
        char* lbase = (char*)WtL;
#pragma unroll
        for (int i = 0; i < 8; i++) {
            int byte = (i * 256 + t) * 16;
            int row = byte >> 8;
            int swz = byte ^ ((row & 7) << 4);
            *(uint4*)(lbase + swz) = *(const uint4*)(gsrc + byte);
        }
    }
    __syncthreads();

    int wave = t >> 6, lane = t & 63;
    int r0w = blockIdx.x * 64 + wave * 16;
    int lrow = lane & 15, lseg = lane >> 4;

    bf16x8 a[4];
    {
        int row = r0w + lrow; if (row >= N) row = N - 1;
        if constexpr (sizeof(TIN) == 4) {
            const float* xp = (const float*)X + (size_t)row * 128 + lseg * 8;
#pragma unroll
            for (int j = 0; j < 4; j++) {
                float4 f0 = *(const float4*)(xp + j * 32);
                float4 f1 = *(const float4*)(xp + j * 32 + 4);
                bf16x8 v;
                v[0] = (short)f2b(f0.x); v[1] = (short)f2b(f0.y);
                v[2] = (short)f2b(f0.z); v[3] = (short)f2b(f0.w);
                v[4] = (short)f2b(f1.x); v[5] = (short)f2b(f1.y);
                v[6] = (short)f2b(f1.z); v[7] = (short)f2b(f1.w);
                a[j] = v;
            }
        } else {
            const u16* xp = (const u16*)X + (size_t)row * 128 + lseg * 8;
#pragma unroll
            for (int j = 0; j < 4; j++) a[j] = *(const bf16x8*)(xp + j * 32);
        }
    }

    f32x4 acc[8];
#pragma unroll
    for (int c = 0; c < 8; c++) acc[c] = (f32x4){0.f, 0.f, 0.f, 0.f};

    const char* lbase = (const char*)WtL;
#pragma unroll
    for (int c = 0; c < 8; c++) {
        int wrow = c * 16 + lrow;
#pragma unroll
        for (int j = 0; j < 4; j++) {
            int byte = wrow * 256 + (j * 32 + lseg * 8) * 2;
            int swz = byte ^ ((wrow & 7) << 4);
            bf16x8 bf = *(const bf16x8*)(lbase + swz);
            acc[c] = __builtin_amdgcn_mfma_f32_16x16x32_bf16(a[j], bf, acc[c], 0, 0, 0);
        }
    }

    float dv[4];
    int rowb = r0w + lseg * 4;
#pragma unroll
    for (int r = 0; r < 4; r++) {
        int row = rowb + r;
        dv[r] = (row < N) ? dinv[row] : 0.f;
    }
    u8* yw = &YL[wave][0];
#pragma unroll
    for (int c = 0; c < 8; c++) {
        u32 p01 = f32x2_to_fp8(acc[c][0] * dv[0], acc[c][1] * dv[1]);
        u32 p23 = f32x2_to_fp8(acc[c][2] * dv[2], acc[c][3] * dv[3]);
        int base = (lseg * 4) * 128 + c * 16 + lrow;
        yw[base]           = (u8)p01;
        yw[base + 128]     = (u8)(p01 >> 8);
        yw[base + 256]     = (u8)p23;
        yw[base + 384]     = (u8)(p23 >> 8);
    }
#pragma unroll
    for (int k = 0; k < 2; k++) {
        int idx = lane + 64 * k;
        int row = idx >> 3;
        int seg = idx & 7;
        int grow = r0w + row;
        uint4 v = *(const uint4*)&yw[row * 128 + seg * 16];
        if (grow < N) *(uint4*)&Y[(size_t)grow * 128 + seg * 16] = v;
    }
}

// -------- aggregation: quad-gather — one wave per node, 4 edges/wave-load ----
// 16-lane groups: group g handles edge e+g, each lane loads 8 B (8 fp8 feats).
// Per-lane 8 f32 accumulators; butterfly shfl_xor(16,32) combines groups.
__global__ __launch_bounds__(256) void k_agg(const u8* __restrict__ Z,
                                             const float* __restrict__ dinv,
                                             const int* __restrict__ row_off,
                                             const int* __restrict__ csr_src,
                                             const float* __restrict__ bias,
                                             u16* __restrict__ OUT, int N, int do_relu) {
    int wave = (blockIdx.x * blockDim.x + threadIdx.x) >> 6;
    int lane = threadIdx.x & 63;
    if (wave >= N) return;
    int g = lane >> 4;          // edge subgroup 0..3
    int fb = (lane & 15) * 8;   // feature base: 8 features per lane
    int beg = row_off[wave], end = row_off[wave + 1];

    float acc[8];
#pragma unroll
    for (int j = 0; j < 8; j++) acc[j] = 0.f;

    // self loop: group 0 only (Z already prescaled by dinv)
    if (g == 0) {
        uint2 v = *(const uint2*)&Z[(size_t)wave * 128 + fb];
        f32x2 f0 = fp8x2_lo(v.x), f1 = fp8x2_hi(v.x);
        f32x2 f2 = fp8x2_lo(v.y), f3 = fp8x2_hi(v.y);
        acc[0] += f0.x; acc[1] += f0.y; acc[2] += f1.x; acc[3] += f1.y;
        acc[4] += f2.x; acc[5] += f2.y; acc[6] += f3.x; acc[7] += f3.y;
    }

    for (int e = beg; e < end; e += 8) {
        int i0 = e + g, i1 = e + 4 + g;
        bool b0 = i0 < end, b1 = i1 < end;
        uint2 v0, v1;
        if (b0) { int s0 = csr_src[i0]; v0 = *(const uint2*)&Z[(size_t)s0 * 128 + fb]; }
        if (b1) { int s1 = csr_src[i1]; v1 = *(const uint2*)&Z[(size_t)s1 * 128 + fb]; }
        if (b0) {
            f32x2 f0 = fp8x2_lo(v0.x), f1 = fp8x2_hi(v0.x);
            f32x2 f2 = fp8x2_lo(v0.y), f3 = fp8x2_hi(v0.y);
            acc[0] += f0.x; acc[1] += f0.y; acc[2] += f1.x; acc[3] += f1.y;
            acc[4] += f2.x; acc[5] += f2.y; acc[6] += f3.x; acc[7] += f3.y;
        }
        if (b1) {
            f32x2 f0 = fp8x2_lo(v1.x), f1 = fp8x2_hi(v1.x);
            f32x2 f2 = fp8x2_lo(v1.y), f3 = fp8x2_hi(v1.y);
            acc[0] += f0.x; acc[1] += f0.y; acc[2] += f1.x; acc[3] += f1.y;
            acc[4] += f2.x; acc[5] += f2.y; acc[6] += f3.x; acc[7] += f3.y;
        }
    }

    // combine the 4 edge subgroups (butterfly: all lanes end with full sums)
#pragma unroll
    for (int j = 0; j < 8; j++) {
        acc[j] += __shfl_xor(acc[j], 16, 64);
        acc[j] += __shfl_xor(acc[j], 32, 64);
    }

    if (g == 0) {
        float din = dinv[wave];
        float4 bb0 = *(const float4*)&bias[fb];
        float4 bb1 = *(const float4*)&bias[fb + 4];
        float o[8];
        o[0] = din * acc[0] + bb0.x; o[1] = din * acc[1] + bb0.y;
        o[2] = din * acc[2] + bb0.z; o[3] = din * acc[3] + bb0.w;
        o[4] = din * acc[4] + bb1.x; o[5] = din * acc[5] + bb1.y;
        o[6] = din * acc[6] + bb1.z; o[7] = din * acc[7] + bb1.w;
        if (do_relu) {
#pragma unroll
            for (int j = 0; j < 8; j++) o[j] = fmaxf(o[j], 0.f);
        }
        u16 ob[8];
#pragma unroll
        for (int j = 0; j < 8; j++) ob[j] = f2b(o[j]);
        *(uint4*)&OUT[(size_t)wave * 128 + fb] = *(uint4*)ob;
    }
}

// ---------------- mean pool per graph (parallel, batch sorted) ----------------
__global__ __launch_bounds__(64) void k_pool_partial(const u16* __restrict__ H,
                                                     const int* __restrict__ batch, int N,
                                                     float* __restrict__ pooled) {
    int t = threadIdx.x;          // feature pair: 2t, 2t+1
    int chunk = (N + gridDim.x - 1) / gridDim.x;
    int beg = blockIdx.x * chunk;
    int end = beg + chunk; if (end > N) end = N;
    if (beg >= end) return;
    float ax = 0.f, ay = 0.f;
    int g = batch[beg];
    for (int nn = beg; nn < end; ++nn) {
        int gn = batch[nn];
        if (gn != g) {
            atomicAdd(&pooled[g * 128 + 2 * t], ax);
            atomicAdd(&pooled[g * 128 + 2 * t + 1], ay);
            ax = 0.f; ay = 0.f;
            g = gn;
        }
        ushort2 v = *(const ushort2*)&H[(size_t)nn * 128 + 2 * t];
        ax += b2f(v.x); ay += b2f(v.y);
    }
    atomicAdd(&pooled[g * 128 + 2 * t], ax);
    atomicAdd(&pooled[g * 128 + 2 * t + 1], ay);
}

__global__ void k_pool_final(const int* __restrict__ batch, int N,
                             float* __restrict__ pooled) {
    int g = blockIdx.x;
    int t = threadIdx.x;
    __shared__ int sh[2];
    if (t == 0) {
        int lo = 0, hi = N;
        while (lo < hi) { int m = (lo + hi) >> 1; if (batch[m] < g) lo = m + 1; else hi = m; }
        sh[0] = lo;
        lo = 0; hi = N;
        while (lo < hi) { int m = (lo + hi) >> 1; if (batch[m] < g + 1) lo = m + 1; else hi = m; }
        sh[1] = lo;
    }
    __syncthreads();
    float cnt = (float)(sh[1] - sh[0]);
    if (cnt < 1.f) cnt = 1.f;
    pooled[g * 128 + t] /= cnt;
}

// ---------------- final MLP ----------------
__global__ void k_mlp(const float* __restrict__ pooled, const float* __restrict__ Wl1,
                      const float* __restrict__ bl1, const float* __restrict__ Wl2,
                      const float* __restrict__ bl2, float* __restrict__ out) {
    int g = blockIdx.x;
    int j = threadIdx.x;
    float acc = 0.f;
#pragma unroll 8
    for (int k = 0; k < 128; k++) acc += pooled[g * 128 + k] * Wl1[k * 64 + j];
    float h = fmaxf(acc + bl1[j], 0.f);
    float v = h * Wl2[j];
#pragma unroll
    for (int off = 32; off > 0; off >>= 1) v += __shfl_down(v, off);
    if (j == 0) out[g] = 1.f / (1.f + expf(-(v + bl2[0])));
}

// ---------------- launch ----------------
extern "C" void kernel_launch(void* const* d_in, const int* in_sizes, int n_in,
                              void* d_out, int out_size, void* d_ws, size_t ws_size,
                              hipStream_t stream) {
    const float* x    = (const float*)d_in[0];
    const int*   edge = (const int*)d_in[1];
    const int*   batch= (const int*)d_in[2];
    const float* W1   = (const float*)d_in[3];
    const float* b1   = (const float*)d_in[4];
    const float* W2   = (const float*)d_in[5];
    const float* b2   = (const float*)d_in[6];
    const float* Wl1  = (const float*)d_in[7];
    const float* bl1  = (const float*)d_in[8];
    const float* Wl2  = (const float*)d_in[9];
    const float* bl2  = (const float*)d_in[10];
    float* out = (float*)d_out;

    int N = in_sizes[0] / 128;
    int E = in_sizes[1] / 2;
    const int* src = edge;
    const int* dst = edge + E;
    int nbuck = (N + (1 << BSHIFT) - 1) >> BSHIFT;

    char* ws = (char*)d_ws;
    size_t off = 0;
    auto alloc = [&](size_t bytes) { void* p = ws + off; off += (bytes + 511) & ~(size_t)511; return p; };
    float* dinv    = (float*)alloc((size_t)N * 4);
    u8*    Z       = (u8*)alloc((size_t)N * 128);        // fp8 gather buffer
    u16*   H       = (u16*)alloc((size_t)N * 128 * 2);   // bf16 agg output
    int*   row_off = (int*)alloc((size_t)(N + 1) * 4);
    int*   csr_src = (int*)alloc((size_t)E * 4);
    u32*   stage   = (u32*)alloc((size_t)E * 4);
    int*   bcnt    = (int*)alloc(256 * 4);
    int*   bbase   = (int*)alloc(260 * 4);
    int*   bkcur   = (int*)alloc(256 * 4);
    float* pooled  = (float*)alloc(64 * 128 * 4);
    u16*   Wt1     = (u16*)alloc(128 * 128 * 2);
    u16*   Wt2     = (u16*)alloc(128 * 128 * 2);

    hipMemsetAsync(bcnt, 0, 256 * 4, stream);
    hipMemsetAsync(bkcur, 0, 256 * 4, stream);
    hipMemsetAsync(pooled, 0, 64 * 128 * 4, stream);

    k_bhist<<<(E + BH_CHUNK - 1) / BH_CHUNK, 256, 0, stream>>>(dst, E, bcnt, nbuck);
    k_bscan<<<1, 256, 0, stream>>>(bcnt, bbase, row_off, nbuck, N, E);
    k_wt<<<2, 256, 0, stream>>>(W1, W2, Wt1, Wt2);
    k_bucketA<<<(E + EPB - 1) / EPB, 256, 0, stream>>>(src, dst, E, bbase, bkcur, stage, nbuck);
    k_bucketB<<<nbuck, 256, 0, stream>>>(stage, bbase, csr_src, row_off, dinv, N);

    k_gemm_mfma<float><<<(N + 63) / 64, 256, 0, stream>>>(x, Wt1, dinv, Z, N);
    k_agg<<<(N + 3) / 4, 256, 0, stream>>>(Z, dinv, row_off, csr_src, b1, H, N, 1);
    k_gemm_mfma<u16><<<(N + 63) / 64, 256, 0, stream>>>(H, Wt2, dinv, Z, N);
    k_agg<<<(N + 3) / 4, 256, 0, stream>>>(Z, dinv, row_off, csr_src, b2, H, N, 0);
    k_pool_partial<<<2048, 64, 0, stream>>>(H, batch, N, pooled);
    k_pool_final<<<64, 128, 0, stream>>>(batch, N, pooled);
    k_mlp<<<64, 64, 0, stream>>>(pooled, Wl1, bl1, Wl2, bl2, out);
}